// Round 2
// baseline (265.282 us; speedup 1.0000x reference)
//
#include <hip/hip_runtime.h>
#include <stdint.h>

typedef unsigned short u16;
typedef __attribute__((ext_vector_type(8))) __bf16 bf16x8;
typedef __attribute__((ext_vector_type(4))) float f32x4;

#define T_LEN 2048
#define NB 16

__device__ __forceinline__ u16 f2bf(float f){
  uint32_t x = __builtin_bit_cast(uint32_t, f);
  x += 0x7FFFu + ((x >> 16) & 1u);
  return (u16)(x >> 16);
}
__device__ __forceinline__ float bf2f(u16 u){
  uint32_t x = ((uint32_t)u) << 16;
  return __builtin_bit_cast(float, x);
}

// joint -> (body part, index within part, part length)
__constant__ int c_part[17] = {1,2,3,1,1,4,4,5,5,2,2,3,3,0,0,0,0};
__constant__ int c_pidx[17] = {0,0,0,1,2,0,1,0,1,1,2,1,2,0,1,2,3};
__constant__ int c_plen[17] = {3,3,3,3,3,2,2,2,2,3,3,3,3,4,4,4,4};

// ---- prep: fold conv+einsum+BN into W1f[272][512], k' = dt*56 + u*3 + ci ----
__global__ void prep_w1(const float* __restrict__ w1, const float* __restrict__ A1,
                        const float* __restrict__ g1, const float* __restrict__ v1,
                        u16* __restrict__ W1f)
{
  int idx = blockIdx.x * 256 + threadIdx.x;
  if (idx >= 272 * 512) return;
  int cw = idx >> 9, kp = idx & 511;
  int c = cw / 17, w = cw - c * 17;
  int dt = kp / 56, r = kp - dt * 56;
  float val = 0.f;
  if (dt < 9 && r < 51){
    int u = r / 3, ci = r - u * 3;
    for (int kk = 0; kk < 5; ++kk)
      for (int dv = 0; dv < 5; ++dv){
        int v = u - dv + 2;
        if (v >= 0 && v < 17)
          val += w1[(kk*16 + c)*135 + ci*45 + dt*5 + dv] * A1[kk*289 + v*17 + w];
      }
    val *= g1[cw] * rsqrtf(v1[cw] + 1e-5f);
  }
  W1f[idx] = f2bf(val);
}

// ---- prep: fold gather+conv+einsum+BN into W2f[96][2464], k' = dt*272 + f*17 + J ----
__global__ void prep_w2(const float* __restrict__ w2, const float* __restrict__ A2,
                        const float* __restrict__ g2, const float* __restrict__ v2,
                        u16* __restrict__ W2f)
{
  int idx = blockIdx.x * 256 + threadIdx.x;
  if (idx >= 96 * 2464) return;
  int cw = idx / 2464, kp = idx - cw * 2464;
  int c = cw / 6, w = cw - c * 6;
  int dt = kp / 272, fj = kp - dt * 272;
  int f = fj / 17, J = fj - f * 17;
  float val = 0.f;
  if (dt < 9){
    int p = c_part[J];
    int ci = f * c_plen[J] + c_pidx[J];
    for (int kk = 0; kk < 5; ++kk)
      for (int dv = 0; dv < 3; ++dv){
        int v = p - dv + 1;
        if (v >= 0 && v < 6)
          val += w2[(kk*16 + c)*1728 + ci*27 + dt*3 + dv] * A2[kk*36 + v*6 + w];
      }
    val *= g2[cw] * rsqrtf(v2[cw] + 1e-5f);
  }
  W2f[idx] = f2bf(val);
}

// ---- prep: W3f[16][480], k' = dt*96 + ch ----
__global__ void prep_w3(const float* __restrict__ w3, const float* __restrict__ g3,
                        const float* __restrict__ v3, u16* __restrict__ W3f)
{
  int idx = blockIdx.x * 256 + threadIdx.x;
  if (idx >= 16 * 480) return;
  int o = idx / 480, kp = idx - o * 480;
  int dt = kp / 96, ch = kp - dt * 96;
  float s = g3[o] * rsqrtf(v3[o] + 1e-5f);
  W3f[idx] = f2bf(s * w3[o*480 + ch*5 + dt]);
}

// ---- prep: W4f[64][64], k' = dt*16 + ch (dt<3 valid) ----
__global__ void prep_w4(const float* __restrict__ w4, const float* __restrict__ g4,
                        const float* __restrict__ v4, u16* __restrict__ W4f)
{
  int idx = blockIdx.x * 256 + threadIdx.x;
  if (idx >= 64 * 64) return;
  int o = idx >> 6, kp = idx & 63;
  int dt = kp >> 4, ch = kp & 15;
  float val = 0.f;
  if (dt < 3){
    float s = g4[o] * rsqrtf(v4[o] + 1e-5f);
    val = s * w4[o*48 + ch*3 + dt];
  }
  W4f[idx] = f2bf(val);
}

__global__ void prep_bias(const float* b1, const float* A1, const float* g1, const float* be1, const float* m1, const float* v1,
                          const float* b2, const float* A2, const float* g2, const float* be2, const float* m2, const float* v2,
                          const float* b3, const float* g3, const float* be3, const float* m3, const float* v3,
                          const float* b4, const float* g4, const float* be4, const float* m4, const float* v4,
                          float* bias1f, float* bias2f, float* bias3f, float* bias4f)
{
  int tid = blockIdx.x * 256 + threadIdx.x;
  if (tid < 272){
    int c = tid / 17, w = tid - c * 17;
    float beff = 0.f;
    for (int kk = 0; kk < 5; ++kk){
      float rs = 0.f;
      for (int v = 0; v < 17; ++v) rs += A1[kk*289 + v*17 + w];
      beff += b1[kk*16 + c] * rs;
    }
    float s = g1[tid] * rsqrtf(v1[tid] + 1e-5f);
    bias1f[tid] = s * (beff - m1[tid]) + be1[tid];
  } else if (tid < 368){
    int cw = tid - 272;
    int c = cw / 6, w = cw - c * 6;
    float beff = 0.f;
    for (int kk = 0; kk < 5; ++kk){
      float rs = 0.f;
      for (int v = 0; v < 6; ++v) rs += A2[kk*36 + v*6 + w];
      beff += b2[kk*16 + c] * rs;
    }
    float s = g2[cw] * rsqrtf(v2[cw] + 1e-5f);
    bias2f[cw] = s * (beff - m2[cw]) + be2[cw];
  } else if (tid < 384){
    int o = tid - 368;
    float s = g3[o] * rsqrtf(v3[o] + 1e-5f);
    bias3f[o] = s * (b3[o] - m3[o]) + be3[o];
  } else if (tid < 448){
    int o = tid - 384;
    float s = g4[o] * rsqrtf(v4[o] + 1e-5f);
    bias4f[o] = s * (b4[o] - m4[o]) + be4[o];
  }
}

// ---- big GEMM (stages 1,2): waves split M-tiles, each wave does 4 n-tiles ----
// B built on-the-fly in LDS from sliding t-window over src[n][t][SRC_R].
template<int MT, int KSTEPS, int RD, int PITCH, int SRC_R, int PAD, int ROWS, int NM, bool IN_F32>
__launch_bounds__(256)
__global__ void gemm_big(const void* __restrict__ src, const u16* __restrict__ Wf,
                         const float* __restrict__ bias, u16* __restrict__ dst)
{
  constexpr int KP = KSTEPS * 32;
  constexpr int MTOT = MT * 16;
  __shared__ u16 patch[ROWS * PITCH];
  const int t0 = blockIdx.x * 64;
  const int n  = blockIdx.y;

  for (int idx = threadIdx.x; idx < ROWS * PITCH; idx += 256){
    int row = idx / PITCH;
    int col = idx - row * PITCH;
    int ts = t0 + row - PAD;
    u16 v = 0;
    if (ts >= 0 && ts < T_LEN && col < SRC_R){
      if constexpr (IN_F32)
        v = f2bf(((const float*)src)[(size_t)(n * T_LEN + ts) * SRC_R + col]);
      else
        v = ((const u16*)src)[(size_t)(n * T_LEN + ts) * SRC_R + col];
    }
    patch[idx] = v;
  }
  __syncthreads();

  const int lane = threadIdx.x & 63;
  const int wv   = threadIdx.x >> 6;
  const int q    = lane >> 4;
  const int l15  = lane & 15;

  f32x4 acc[NM][4];
#pragma unroll
  for (int i = 0; i < NM; ++i)
#pragma unroll
    for (int j = 0; j < 4; ++j)
      acc[i][j] = (f32x4){0.f, 0.f, 0.f, 0.f};

  for (int ks = 0; ks < KSTEPS; ++ks){
    const int k0 = ks * 32 + q * 8;
    const int dt = k0 / RD;
    const int r  = k0 - dt * RD;
    bf16x8 bfrag[4];
#pragma unroll
    for (int nt = 0; nt < 4; ++nt){
      const int trow = nt * 16 + l15 + dt;
      bfrag[nt] = *reinterpret_cast<const bf16x8*>(&patch[trow * PITCH + r]);
    }
#pragma unroll
    for (int i = 0; i < NM; ++i){
      const int mt = wv + i * 4;
      if (mt < MT){
        const bf16x8 afrag = *reinterpret_cast<const bf16x8*>(&Wf[(size_t)(mt * 16 + l15) * KP + k0]);
#pragma unroll
        for (int nt = 0; nt < 4; ++nt)
          acc[i][nt] = __builtin_amdgcn_mfma_f32_16x16x32_bf16(afrag, bfrag[nt], acc[i][nt], 0, 0, 0);
      }
    }
  }

#pragma unroll
  for (int i = 0; i < NM; ++i){
    const int mt = wv + i * 4;
    if (mt >= MT) continue;
    const int chb = mt * 16 + q * 4;
    const float b0 = bias[chb+0], b1 = bias[chb+1], b2 = bias[chb+2], b3 = bias[chb+3];
#pragma unroll
    for (int nt = 0; nt < 4; ++nt){
      const int t = t0 + nt * 16 + l15;
      ushort4 o;
      o.x = f2bf(acc[i][nt][0] + b0);
      o.y = f2bf(acc[i][nt][1] + b1);
      o.z = f2bf(acc[i][nt][2] + b2);
      o.w = f2bf(acc[i][nt][3] + b3);
      *reinterpret_cast<ushort4*>(&dst[(size_t)(n * T_LEN + t) * MTOT + chb]) = o;
    }
  }
}

// ---- small GEMM (stages 3,4): wave = n-tile, all M-tiles per wave, leaky epilogue ----
template<int MT, int KSTEPS, int RD, int PITCH, int SRC_R, int PAD, int ROWS, int OSTR, bool OUT_F32>
__launch_bounds__(256)
__global__ void gemm_small(const u16* __restrict__ src, const u16* __restrict__ Wf,
                           const float* __restrict__ bias, void* __restrict__ dst)
{
  constexpr int KP = KSTEPS * 32;
  __shared__ u16 patch[ROWS * PITCH];
  const int t0 = blockIdx.x * 64;
  const int n  = blockIdx.y;

  for (int idx = threadIdx.x; idx < ROWS * PITCH; idx += 256){
    int row = idx / PITCH;
    int col = idx - row * PITCH;
    int ts = t0 + row - PAD;
    u16 v = 0;
    if (ts >= 0 && ts < T_LEN && col < SRC_R) v = src[(size_t)(n * T_LEN + ts) * SRC_R + col];
    patch[idx] = v;
  }
  __syncthreads();

  const int lane = threadIdx.x & 63;
  const int nt   = threadIdx.x >> 6;
  const int q    = lane >> 4;
  const int l15  = lane & 15;

  f32x4 acc[MT];
#pragma unroll
  for (int i = 0; i < MT; ++i) acc[i] = (f32x4){0.f, 0.f, 0.f, 0.f};

  for (int ks = 0; ks < KSTEPS; ++ks){
    const int k0 = ks * 32 + q * 8;
    const int dt = k0 / RD;
    const int r  = k0 - dt * RD;
    const int trow = nt * 16 + l15 + dt;
    const bf16x8 bfrag = *reinterpret_cast<const bf16x8*>(&patch[trow * PITCH + r]);
#pragma unroll
    for (int mt = 0; mt < MT; ++mt){
      const bf16x8 afrag = *reinterpret_cast<const bf16x8*>(&Wf[(size_t)(mt * 16 + l15) * KP + k0]);
      acc[mt] = __builtin_amdgcn_mfma_f32_16x16x32_bf16(afrag, bfrag, acc[mt], 0, 0, 0);
    }
  }

#pragma unroll
  for (int mt = 0; mt < MT; ++mt){
    const int chb = mt * 16 + q * 4;
    const int t = t0 + nt * 16 + l15;
    float v0 = acc[mt][0] + bias[chb+0];
    float v1 = acc[mt][1] + bias[chb+1];
    float v2 = acc[mt][2] + bias[chb+2];
    float v3 = acc[mt][3] + bias[chb+3];
    v0 = v0 > 0.f ? v0 : 0.01f * v0;
    v1 = v1 > 0.f ? v1 : 0.01f * v1;
    v2 = v2 > 0.f ? v2 : 0.01f * v2;
    v3 = v3 > 0.f ? v3 : 0.01f * v3;
    if constexpr (OUT_F32){
      float4 o; o.x = v0; o.y = v1; o.z = v2; o.w = v3;
      *reinterpret_cast<float4*>(&((float*)dst)[(size_t)(n * T_LEN + t) * OSTR + chb]) = o;
    } else {
      ushort4 o;
      o.x = f2bf(v0); o.y = f2bf(v1); o.z = f2bf(v2); o.w = f2bf(v3);
      *reinterpret_cast<ushort4*>(&((u16*)dst)[(size_t)(n * T_LEN + t) * OSTR + chb]) = o;
    }
  }
}

extern "C" void kernel_launch(void* const* d_in, const int* in_sizes, int n_in,
                              void* d_out, int out_size, void* d_ws, size_t ws_size,
                              hipStream_t stream)
{
  const float* poses = (const float*)d_in[0];
  const float* A1  = (const float*)d_in[1];
  const float* A2  = (const float*)d_in[2];
  const float* w1  = (const float*)d_in[3];
  const float* b1  = (const float*)d_in[4];
  const float* g1  = (const float*)d_in[5];
  const float* be1 = (const float*)d_in[6];
  const float* m1  = (const float*)d_in[7];
  const float* v1  = (const float*)d_in[8];
  const float* w2  = (const float*)d_in[9];
  const float* b2  = (const float*)d_in[10];
  const float* g2  = (const float*)d_in[11];
  const float* be2 = (const float*)d_in[12];
  const float* m2  = (const float*)d_in[13];
  const float* v2  = (const float*)d_in[14];
  const float* w3  = (const float*)d_in[15];
  const float* b3  = (const float*)d_in[16];
  const float* g3  = (const float*)d_in[17];
  const float* be3 = (const float*)d_in[18];
  const float* m3  = (const float*)d_in[19];
  const float* v3  = (const float*)d_in[20];
  const float* w4  = (const float*)d_in[21];
  const float* b4  = (const float*)d_in[22];
  const float* g4  = (const float*)d_in[23];
  const float* be4 = (const float*)d_in[24];
  const float* m4  = (const float*)d_in[25];
  const float* v4  = (const float*)d_in[26];

  uint8_t* ws = (uint8_t*)d_ws;
  size_t off = 0;
  auto alloc = [&](size_t bytes) -> void* {
    void* p = ws + off;
    off += (bytes + 255) & ~(size_t)255;
    return p;
  };
  u16* W1f = (u16*)alloc(272 * 512 * 2);
  u16* W2f = (u16*)alloc(96 * 2464 * 2);
  u16* W3f = (u16*)alloc(16 * 480 * 2);
  u16* W4f = (u16*)alloc(64 * 64 * 2);
  float* bias1f = (float*)alloc(272 * 4);
  float* bias2f = (float*)alloc(96 * 4);
  float* bias3f = (float*)alloc(16 * 4);
  float* bias4f = (float*)alloc(64 * 4);
  u16* X1 = (u16*)alloc((size_t)NB * T_LEN * 272 * 2);
  u16* X2 = (u16*)alloc((size_t)NB * T_LEN * 96 * 2);
  u16* X3 = (u16*)alloc((size_t)NB * T_LEN * 16 * 2);

  hipLaunchKernelGGL(prep_w1, dim3(544), dim3(256), 0, stream, w1, A1, g1, v1, W1f);
  hipLaunchKernelGGL(prep_w2, dim3(924), dim3(256), 0, stream, w2, A2, g2, v2, W2f);
  hipLaunchKernelGGL(prep_w3, dim3(30), dim3(256), 0, stream, w3, g3, v3, W3f);
  hipLaunchKernelGGL(prep_w4, dim3(16), dim3(256), 0, stream, w4, g4, v4, W4f);
  hipLaunchKernelGGL(prep_bias, dim3(2), dim3(256), 0, stream,
                     b1, A1, g1, be1, m1, v1,
                     b2, A2, g2, be2, m2, v2,
                     b3, g3, be3, m3, v3,
                     b4, g4, be4, m4, v4,
                     bias1f, bias2f, bias3f, bias4f);

  dim3 grid(T_LEN / 64, NB);
  hipLaunchKernelGGL((gemm_big<17, 16, 56, 56, 51, 4, 76, 5, true>),   grid, dim3(256), 0, stream, (const void*)poses, W1f, bias1f, X1);
  hipLaunchKernelGGL((gemm_big<6, 77, 272, 280, 272, 4, 76, 2, false>), grid, dim3(256), 0, stream, (const void*)X1, W2f, bias2f, X2);
  hipLaunchKernelGGL((gemm_small<1, 15, 96, 104, 96, 2, 68, 16, false>), grid, dim3(256), 0, stream, X2, W3f, bias3f, X3);
  hipLaunchKernelGGL((gemm_small<4, 2, 16, 24, 16, 1, 68, 64, true>),   grid, dim3(256), 0, stream, X3, W4f, bias4f, d_out);
}

// Round 3
// 210.486 us; speedup vs baseline: 1.2603x; 1.2603x over previous
//
#include <hip/hip_runtime.h>
#include <stdint.h>

typedef unsigned short u16;
typedef __attribute__((ext_vector_type(8))) __bf16 bf16x8;
typedef __attribute__((ext_vector_type(8))) u16 u16x8;
typedef __attribute__((ext_vector_type(4))) float f32x4;

#define T_LEN 2048
#define NB 16

__device__ __forceinline__ u16 f2bf(float f){
  uint32_t x = __builtin_bit_cast(uint32_t, f);
  x += 0x7FFFu + ((x >> 16) & 1u);
  return (u16)(x >> 16);
}

// joint -> (body part, index within part, part length)
__constant__ int c_part[17] = {1,2,3,1,1,4,4,5,5,2,2,3,3,0,0,0,0};
__constant__ int c_pidx[17] = {0,0,0,1,2,0,1,0,1,1,2,1,2,0,1,2,3};
__constant__ int c_plen[17] = {3,3,3,3,3,2,2,2,2,3,3,3,3,4,4,4,4};

// ---- prep: fold conv+einsum+BN into W1f[272][512], k' = dt*56 + u*3 + ci ----
__global__ void prep_w1(const float* __restrict__ w1, const float* __restrict__ A1,
                        const float* __restrict__ g1, const float* __restrict__ v1,
                        u16* __restrict__ W1f)
{
  int idx = blockIdx.x * 256 + threadIdx.x;
  if (idx >= 272 * 512) return;
  int cw = idx >> 9, kp = idx & 511;
  int c = cw / 17, w = cw - c * 17;
  int dt = kp / 56, r = kp - dt * 56;
  float val = 0.f;
  if (dt < 9 && r < 51){
    int u = r / 3, ci = r - u * 3;
    for (int kk = 0; kk < 5; ++kk)
      for (int dv = 0; dv < 5; ++dv){
        int v = u - dv + 2;
        if (v >= 0 && v < 17)
          val += w1[(kk*16 + c)*135 + ci*45 + dt*5 + dv] * A1[kk*289 + v*17 + w];
      }
    val *= g1[cw] * rsqrtf(v1[cw] + 1e-5f);
  }
  W1f[idx] = f2bf(val);
}

// ---- prep: fold gather+conv+einsum+BN into W2f[96][2464], k' = dt*272 + f*17 + J ----
__global__ void prep_w2(const float* __restrict__ w2, const float* __restrict__ A2,
                        const float* __restrict__ g2, const float* __restrict__ v2,
                        u16* __restrict__ W2f)
{
  int idx = blockIdx.x * 256 + threadIdx.x;
  if (idx >= 96 * 2464) return;
  int cw = idx / 2464, kp = idx - cw * 2464;
  int c = cw / 6, w = cw - c * 6;
  int dt = kp / 272, fj = kp - dt * 272;
  int f = fj / 17, J = fj - f * 17;
  float val = 0.f;
  if (dt < 9){
    int p = c_part[J];
    int ci = f * c_plen[J] + c_pidx[J];
    for (int kk = 0; kk < 5; ++kk)
      for (int dv = 0; dv < 3; ++dv){
        int v = p - dv + 1;
        if (v >= 0 && v < 6)
          val += w2[(kk*16 + c)*1728 + ci*27 + dt*3 + dv] * A2[kk*36 + v*6 + w];
      }
    val *= g2[cw] * rsqrtf(v2[cw] + 1e-5f);
  }
  W2f[idx] = f2bf(val);
}

// ---- fused small preps: W3f[16][480] (k'=dt*96+ch), W4f[64][64] (k'=dt*16+ch), all biases ----
__global__ void prep_small(const float* w3, const float* g3, const float* v3, u16* W3f,
                           const float* w4, const float* g4, const float* v4, u16* W4f,
                           const float* b1, const float* A1, const float* g1, const float* be1, const float* m1, const float* v1,
                           const float* b2, const float* A2, const float* g2, const float* be2, const float* m2, const float* v2,
                           const float* b3, const float* be3, const float* m3,
                           const float* b4, const float* be4, const float* m4,
                           float* bias1f, float* bias2f, float* bias3f, float* bias4f)
{
  int idx = blockIdx.x * 256 + threadIdx.x;
  if (idx < 7680){
    int o = idx / 480, kp = idx - o * 480;
    int dt = kp / 96, ch = kp - dt * 96;
    float s = g3[o] * rsqrtf(v3[o] + 1e-5f);
    W3f[idx] = f2bf(s * w3[o*480 + ch*5 + dt]);
    return;
  }
  idx -= 7680;
  if (idx < 4096){
    int o = idx >> 6, kp = idx & 63;
    int dt = kp >> 4, ch = kp & 15;
    float val = 0.f;
    if (dt < 3){
      float s = g4[o] * rsqrtf(v4[o] + 1e-5f);
      val = s * w4[o*48 + ch*3 + dt];
    }
    W4f[idx] = f2bf(val);
    return;
  }
  int tid = idx - 4096;
  if (tid < 272){
    int c = tid / 17, w = tid - c * 17;
    float beff = 0.f;
    for (int kk = 0; kk < 5; ++kk){
      float rs = 0.f;
      for (int v = 0; v < 17; ++v) rs += A1[kk*289 + v*17 + w];
      beff += b1[kk*16 + c] * rs;
    }
    float s = g1[tid] * rsqrtf(v1[tid] + 1e-5f);
    bias1f[tid] = s * (beff - m1[tid]) + be1[tid];
  } else if (tid < 368){
    int cw = tid - 272;
    int c = cw / 6, w = cw - c * 6;
    float beff = 0.f;
    for (int kk = 0; kk < 5; ++kk){
      float rs = 0.f;
      for (int v = 0; v < 6; ++v) rs += A2[kk*36 + v*6 + w];
      beff += b2[kk*16 + c] * rs;
    }
    float s = g2[cw] * rsqrtf(v2[cw] + 1e-5f);
    bias2f[cw] = s * (beff - m2[cw]) + be2[cw];
  } else if (tid < 384){
    int o = tid - 368;
    float s = g3[o] * rsqrtf(v3[o] + 1e-5f);
    bias3f[o] = s * (b3[o] - m3[o]) + be3[o];
  } else if (tid < 448){
    int o = tid - 384;
    float s = g4[o] * rsqrtf(v4[o] + 1e-5f);
    bias4f[o] = s * (b4[o] - m4[o]) + be4[o];
  }
}

// ---- big GEMM (stages 1,2): block = 64 t (4 n-tiles), 4 waves.
// Wave = (M-group h = wv%NMH) x (n-tile group p = wv/NMH of NT=NMH tiles).
// M-tiles: mt = h + i*NMH (i<NM). Distance-1 double-buffered prefetch:
// A frags from global (L2-resident folded weights), B frags from LDS patch.
template<int MT, int KSTEPS, int RD, int PITCH, int SRC_R, int NM, int NMH, bool IN_F32>
__launch_bounds__(256)
__global__ void gemm_big(const void* __restrict__ src, const u16* __restrict__ Wf,
                         const float* __restrict__ bias, u16* __restrict__ dst)
{
  constexpr int KP = KSTEPS * 32;
  constexpr int NT = NMH;           // n-tiles per wave
  constexpr int MTOT = MT * 16;
  constexpr int ROWS = 76;          // 64 + 4 front pad + 8 back halo
  __shared__ u16 patch[ROWS * PITCH];
  const int t0 = blockIdx.x * 64;
  const int n  = blockIdx.y;
  const int tid = threadIdx.x;

  // ---- stage patch: rows = t0-4 .. t0+71, cols 0..SRC_R (zero-padded to PITCH) ----
  if constexpr (IN_F32){
    for (int idx = tid; idx < ROWS * PITCH; idx += 256){
      int row = idx / PITCH, col = idx - row * PITCH;
      int ts = t0 + row - 4;
      u16 v = 0;
      if (ts >= 0 && ts < T_LEN && col < SRC_R)
        v = f2bf(((const float*)src)[((size_t)n * T_LEN + ts) * SRC_R + col]);
      patch[idx] = v;
    }
  } else {
    constexpr int GP = PITCH / 8;
    for (int idx = tid; idx < ROWS * GP; idx += 256){
      int row = idx / GP, g = idx - row * GP;
      int ts = t0 + row - 4;
      int col = g * 8;
      u16x8 v = (u16x8)0;
      if (ts >= 0 && ts < T_LEN && col + 8 <= SRC_R)
        v = *reinterpret_cast<const u16x8*>(&((const u16*)src)[((size_t)n * T_LEN + ts) * SRC_R + col]);
      *reinterpret_cast<u16x8*>(&patch[row * PITCH + col]) = v;
    }
  }
  __syncthreads();

  const int lane = tid & 63;
  const int wv   = tid >> 6;
  const int q    = lane >> 4;
  const int l15  = lane & 15;
  const int h    = wv % NMH;        // M-group
  const int p    = wv / NMH;        // n-tile group

  int abase[NM];
  bool mok[NM];
#pragma unroll
  for (int i = 0; i < NM; ++i){
    int mtv = h + i * NMH;
    mok[i] = (mtv < MT);
    int mc = mok[i] ? mtv : 0;
    abase[i] = (mc * 16 + l15) * KP;
  }
  int bbase[NT];
#pragma unroll
  for (int j = 0; j < NT; ++j)
    bbase[j] = ((p * NT + j) * 16 + l15) * PITCH;

  f32x4 acc[NM][NT];
#pragma unroll
  for (int i = 0; i < NM; ++i)
#pragma unroll
    for (int j = 0; j < NT; ++j)
      acc[i][j] = (f32x4){0.f, 0.f, 0.f, 0.f};

  bf16x8 aF[2][NM];
  bf16x8 bF[2][NT];

  auto loadstep = [&](int buf, int ks){
    const int k0 = ks * 32 + q * 8;
    const int dt = k0 / RD;
    const int r  = k0 - dt * RD;
    const int od = dt * PITCH + r;
#pragma unroll
    for (int j = 0; j < NT; ++j)
      bF[buf][j] = *reinterpret_cast<const bf16x8*>(&patch[bbase[j] + od]);
#pragma unroll
    for (int i = 0; i < NM; ++i)
      aF[buf][i] = *reinterpret_cast<const bf16x8*>(&Wf[abase[i] + k0]);
  };
  auto mfmastep = [&](int buf){
#pragma unroll
    for (int i = 0; i < NM; ++i){
      if (!mok[i]) continue;
#pragma unroll
      for (int j = 0; j < NT; ++j)
        acc[i][j] = __builtin_amdgcn_mfma_f32_16x16x32_bf16(aF[buf][i], bF[buf][j], acc[i][j], 0, 0, 0);
    }
  };

  loadstep(0, 0);
  for (int ks = 0; ks + 2 <= KSTEPS; ks += 2){
    loadstep(1, ks + 1);
    mfmastep(0);
    if (ks + 2 < KSTEPS) loadstep(0, ks + 2);
    mfmastep(1);
  }
  if constexpr (KSTEPS & 1) mfmastep(0);

#pragma unroll
  for (int i = 0; i < NM; ++i){
    if (!mok[i]) continue;
    const int chb = (h + i * NMH) * 16 + q * 4;
    const float b0 = bias[chb+0], b1 = bias[chb+1], b2 = bias[chb+2], b3 = bias[chb+3];
#pragma unroll
    for (int j = 0; j < NT; ++j){
      const int t = t0 + (p * NT + j) * 16 + l15;
      ushort4 o;
      o.x = f2bf(acc[i][j][0] + b0);
      o.y = f2bf(acc[i][j][1] + b1);
      o.z = f2bf(acc[i][j][2] + b2);
      o.w = f2bf(acc[i][j][3] + b3);
      *reinterpret_cast<ushort4*>(&dst[((size_t)n * T_LEN + t) * MTOT + chb]) = o;
    }
  }
}

// ---- small GEMM (stages 3,4): block = 128 thr (2 waves), 32 t; wave = 1 n-tile, all M-tiles.
template<int MT, int KSTEPS, int RD, int PITCH, int SRC_R, int PAD, int ROWS, int OSTR, bool OUT_F32>
__launch_bounds__(128)
__global__ void gemm_small(const u16* __restrict__ src, const u16* __restrict__ Wf,
                           const float* __restrict__ bias, void* __restrict__ dst)
{
  constexpr int KP = KSTEPS * 32;
  constexpr int GP = PITCH / 8;
  __shared__ u16 patch[ROWS * PITCH];
  const int t0 = blockIdx.x * 32;
  const int n  = blockIdx.y;
  const int tid = threadIdx.x;

  for (int idx = tid; idx < ROWS * GP; idx += 128){
    int row = idx / GP, g = idx - row * GP;
    int ts = t0 + row - PAD;
    int col = g * 8;
    u16x8 v = (u16x8)0;
    if (ts >= 0 && ts < T_LEN && col + 8 <= SRC_R)
      v = *reinterpret_cast<const u16x8*>(&src[((size_t)n * T_LEN + ts) * SRC_R + col]);
    *reinterpret_cast<u16x8*>(&patch[row * PITCH + col]) = v;
  }
  __syncthreads();

  const int lane = tid & 63;
  const int nt   = tid >> 6;
  const int q    = lane >> 4;
  const int l15  = lane & 15;
  const int bb   = (nt * 16 + l15) * PITCH;

  f32x4 acc[MT];
#pragma unroll
  for (int i = 0; i < MT; ++i) acc[i] = (f32x4){0.f, 0.f, 0.f, 0.f};

  bf16x8 aF[2][MT];
  bf16x8 bF[2];

  auto loadstep = [&](int buf, int ks){
    const int k0 = ks * 32 + q * 8;
    const int dt = k0 / RD;
    const int r  = k0 - dt * RD;
    bF[buf] = *reinterpret_cast<const bf16x8*>(&patch[bb + dt * PITCH + r]);
#pragma unroll
    for (int mt = 0; mt < MT; ++mt)
      aF[buf][mt] = *reinterpret_cast<const bf16x8*>(&Wf[(mt * 16 + l15) * KP + k0]);
  };
  auto mfmastep = [&](int buf){
#pragma unroll
    for (int mt = 0; mt < MT; ++mt)
      acc[mt] = __builtin_amdgcn_mfma_f32_16x16x32_bf16(aF[buf][mt], bF[buf], acc[mt], 0, 0, 0);
  };

  loadstep(0, 0);
  for (int ks = 0; ks + 2 <= KSTEPS; ks += 2){
    loadstep(1, ks + 1);
    mfmastep(0);
    if (ks + 2 < KSTEPS) loadstep(0, ks + 2);
    mfmastep(1);
  }
  if constexpr (KSTEPS & 1) mfmastep(0);

#pragma unroll
  for (int mt = 0; mt < MT; ++mt){
    const int chb = mt * 16 + q * 4;
    const int t = t0 + nt * 16 + l15;
    float v0 = acc[mt][0] + bias[chb+0];
    float v1 = acc[mt][1] + bias[chb+1];
    float v2 = acc[mt][2] + bias[chb+2];
    float v3 = acc[mt][3] + bias[chb+3];
    v0 = v0 > 0.f ? v0 : 0.01f * v0;
    v1 = v1 > 0.f ? v1 : 0.01f * v1;
    v2 = v2 > 0.f ? v2 : 0.01f * v2;
    v3 = v3 > 0.f ? v3 : 0.01f * v3;
    if constexpr (OUT_F32){
      float4 o; o.x = v0; o.y = v1; o.z = v2; o.w = v3;
      *reinterpret_cast<float4*>(&((float*)dst)[((size_t)n * T_LEN + t) * OSTR + chb]) = o;
    } else {
      ushort4 o;
      o.x = f2bf(v0); o.y = f2bf(v1); o.z = f2bf(v2); o.w = f2bf(v3);
      *reinterpret_cast<ushort4*>(&((u16*)dst)[((size_t)n * T_LEN + t) * OSTR + chb]) = o;
    }
  }
}

extern "C" void kernel_launch(void* const* d_in, const int* in_sizes, int n_in,
                              void* d_out, int out_size, void* d_ws, size_t ws_size,
                              hipStream_t stream)
{
  const float* poses = (const float*)d_in[0];
  const float* A1  = (const float*)d_in[1];
  const float* A2  = (const float*)d_in[2];
  const float* w1  = (const float*)d_in[3];
  const float* b1  = (const float*)d_in[4];
  const float* g1  = (const float*)d_in[5];
  const float* be1 = (const float*)d_in[6];
  const float* m1  = (const float*)d_in[7];
  const float* v1  = (const float*)d_in[8];
  const float* w2  = (const float*)d_in[9];
  const float* b2  = (const float*)d_in[10];
  const float* g2  = (const float*)d_in[11];
  const float* be2 = (const float*)d_in[12];
  const float* m2  = (const float*)d_in[13];
  const float* v2  = (const float*)d_in[14];
  const float* w3  = (const float*)d_in[15];
  const float* b3  = (const float*)d_in[16];
  const float* g3  = (const float*)d_in[17];
  const float* be3 = (const float*)d_in[18];
  const float* m3  = (const float*)d_in[19];
  const float* v3  = (const float*)d_in[20];
  const float* w4  = (const float*)d_in[21];
  const float* b4  = (const float*)d_in[22];
  const float* g4  = (const float*)d_in[23];
  const float* be4 = (const float*)d_in[24];
  const float* m4  = (const float*)d_in[25];
  const float* v4  = (const float*)d_in[26];

  uint8_t* ws = (uint8_t*)d_ws;
  size_t off = 0;
  auto alloc = [&](size_t bytes) -> void* {
    void* p = ws + off;
    off += (bytes + 255) & ~(size_t)255;
    return p;
  };
  u16* W1f = (u16*)alloc(272 * 512 * 2);
  u16* W2f = (u16*)alloc(96 * 2464 * 2);
  u16* W3f = (u16*)alloc(16 * 480 * 2);
  u16* W4f = (u16*)alloc(64 * 64 * 2);
  float* bias1f = (float*)alloc(272 * 4);
  float* bias2f = (float*)alloc(96 * 4);
  float* bias3f = (float*)alloc(16 * 4);
  float* bias4f = (float*)alloc(64 * 4);
  u16* X1 = (u16*)alloc((size_t)NB * T_LEN * 272 * 2);
  u16* X2 = (u16*)alloc((size_t)NB * T_LEN * 96 * 2);
  u16* X3 = (u16*)alloc((size_t)NB * T_LEN * 16 * 2);

  hipLaunchKernelGGL(prep_w1, dim3(544), dim3(256), 0, stream, w1, A1, g1, v1, W1f);
  hipLaunchKernelGGL(prep_w2, dim3(924), dim3(256), 0, stream, w2, A2, g2, v2, W2f);
  hipLaunchKernelGGL(prep_small, dim3(48), dim3(256), 0, stream,
                     w3, g3, v3, W3f, w4, g4, v4, W4f,
                     b1, A1, g1, be1, m1, v1,
                     b2, A2, g2, be2, m2, v2,
                     b3, be3, m3, b4, be4, m4,
                     bias1f, bias2f, bias3f, bias4f);

  dim3 gridB(T_LEN / 64, NB);
  dim3 gridS(T_LEN / 32, NB);
  // stage1: MT=17, K=512 (16 ks), RD=56, NM=5, NMH=4 (wave: M-quarter x 4 n-tiles)
  hipLaunchKernelGGL((gemm_big<17, 16, 56, 56, 51, 5, 4, true>),    gridB, dim3(256), 0, stream, (const void*)poses, W1f, bias1f, X1);
  // stage2: MT=6, K=2464 (77 ks), RD=272, NM=3, NMH=2 (wave: M-half x 2 n-tiles)
  hipLaunchKernelGGL((gemm_big<6, 77, 272, 280, 272, 3, 2, false>), gridB, dim3(256), 0, stream, (const void*)X1, W2f, bias2f, X2);
  // stage3: MT=1, K=480 (15 ks), RD=96, pad 2, rows 36
  hipLaunchKernelGGL((gemm_small<1, 15, 96, 104, 96, 2, 36, 16, false>), gridS, dim3(128), 0, stream, X2, W3f, bias3f, X3);
  // stage4: MT=4, K=64 (2 ks), RD=16, pad 1, rows 35, f32 out
  hipLaunchKernelGGL((gemm_small<4, 2, 16, 24, 16, 1, 35, 64, true>),    gridS, dim3(128), 0, stream, X3, W4f, bias4f, d_out);
}

// Round 4
// 173.139 us; speedup vs baseline: 1.5322x; 1.2157x over previous
//
#include <hip/hip_runtime.h>
#include <stdint.h>

typedef unsigned short u16;
typedef __attribute__((ext_vector_type(8))) __bf16 bf16x8;
typedef __attribute__((ext_vector_type(8))) u16 u16x8;
typedef __attribute__((ext_vector_type(4))) float f32x4;

#define T_LEN 2048
#define NB 16

__device__ __forceinline__ u16 f2bf(float f){
  uint32_t x = __builtin_bit_cast(uint32_t, f);
  x += 0x7FFFu + ((x >> 16) & 1u);
  return (u16)(x >> 16);
}

// joint -> (body part, index within part, part length)
__constant__ int c_part[17] = {1,2,3,1,1,4,4,5,5,2,2,3,3,0,0,0,0};
__constant__ int c_pidx[17] = {0,0,0,1,2,0,1,0,1,1,2,1,2,0,1,2,3};
__constant__ int c_plen[17] = {3,3,3,3,3,2,2,2,2,3,3,3,3,4,4,4,4};

// ---- all weight folds + biases, ONE launch. Weights written in MFMA
// fragment order: fidx = (ks*MT + mt)*512 + lane*8 + j, lane = q*16 + r.
__global__ void prep_all(
  const float* __restrict__ w1, const float* __restrict__ A1, const float* __restrict__ g1, const float* __restrict__ v1, u16* __restrict__ W1f,
  const float* __restrict__ w2, const float* __restrict__ A2, const float* __restrict__ g2, const float* __restrict__ v2, u16* __restrict__ W2f,
  const float* __restrict__ w3, const float* __restrict__ g3, const float* __restrict__ v3, u16* __restrict__ W3f,
  const float* __restrict__ w4, const float* __restrict__ g4, const float* __restrict__ v4, u16* __restrict__ W4f,
  const float* b1, const float* be1, const float* m1,
  const float* b2, const float* be2, const float* m2,
  const float* b3, const float* be3, const float* m3,
  const float* b4, const float* be4, const float* m4,
  float* bias1f, float* bias2f, float* bias3f, float* bias4f)
{
  const int bid = blockIdx.x;
  if (bid < 544){
    // W1f[272][512], k' = dt*56 + u*3 + ci, MT=17, 16 ksteps
    int idx = bid * 256 + threadIdx.x;          // < 139264 exact
    int cw = idx >> 9, kp = idx & 511;
    int c = cw / 17, w = cw - c * 17;
    int dt = kp / 56, r0 = kp - dt * 56;
    float val = 0.f;
    if (dt < 9 && r0 < 51){
      int u = r0 / 3, ci = r0 - u * 3;
      for (int kk = 0; kk < 5; ++kk)
        for (int dv = 0; dv < 5; ++dv){
          int v = u - dv + 2;
          if (v >= 0 && v < 17)
            val += w1[(kk*16 + c)*135 + ci*45 + dt*5 + dv] * A1[kk*289 + v*17 + w];
        }
      val *= g1[cw] * rsqrtf(v1[cw] + 1e-5f);
    }
    int mt = cw >> 4, r = cw & 15, ks = kp >> 5, kq = kp & 31;
    W1f[(ks*17 + mt)*512 + ((kq>>3)*16 + r)*8 + (kq&7)] = f2bf(val);
  } else if (bid < 1480){
    // W2f[96][2496], k' = dt*272 + f*17 + J, MT=6, 78 ksteps (real K=2448)
    int idx = (bid - 544) * 256 + threadIdx.x;  // < 239616 exact
    int cw = idx / 2496, kp = idx - cw * 2496;
    int c = cw / 6, w = cw - c * 6;
    int dt = kp / 272, fj = kp - dt * 272;
    float val = 0.f;
    if (dt < 9){
      int f = fj / 17, J = fj - f * 17;
      int p = c_part[J];
      int ci = f * c_plen[J] + c_pidx[J];
      for (int kk = 0; kk < 5; ++kk)
        for (int dv = 0; dv < 3; ++dv){
          int v = p - dv + 1;
          if (v >= 0 && v < 6)
            val += w2[(kk*16 + c)*1728 + ci*27 + dt*3 + dv] * A2[kk*36 + v*6 + w];
        }
      val *= g2[cw] * rsqrtf(v2[cw] + 1e-5f);
    }
    int mt = cw >> 4, r = cw & 15, ks = kp >> 5, kq = kp & 31;
    W2f[(ks*6 + mt)*512 + ((kq>>3)*16 + r)*8 + (kq&7)] = f2bf(val);
  } else {
    int idx = (bid - 1480) * 256 + threadIdx.x;
    if (idx < 8192){
      // W3f[16][512], k' = dt*96 + ch (dt<5), MT=1, 16 ksteps
      int cw = idx >> 9, kp = idx & 511;
      int dt = kp / 96, ch = kp - dt * 96;
      float val = 0.f;
      if (dt < 5){
        float s = g3[cw] * rsqrtf(v3[cw] + 1e-5f);
        val = s * w3[cw*480 + ch*5 + dt];
      }
      int ks = kp >> 5, kq = kp & 31;
      W3f[ks*512 + ((kq>>3)*16 + cw)*8 + (kq&7)] = f2bf(val);
    } else if (idx < 12288){
      // W4f[64][64], k' = dt*16 + ch (dt<3), MT=4, 2 ksteps
      int i2 = idx - 8192;
      int cw = i2 >> 6, kp = i2 & 63;
      int dt = kp >> 4, ch = kp & 15;
      float val = 0.f;
      if (dt < 3){
        float s = g4[cw] * rsqrtf(v4[cw] + 1e-5f);
        val = s * w4[cw*48 + ch*3 + dt];
      }
      int mt = cw >> 4, r = cw & 15, ks = kp >> 5, kq = kp & 31;
      W4f[(ks*4 + mt)*512 + ((kq>>3)*16 + r)*8 + (kq&7)] = f2bf(val);
    } else if (idx < 12736){
      int tid = idx - 12288;
      if (tid < 272){
        int c = tid / 17, w = tid - c * 17;
        float beff = 0.f;
        for (int kk = 0; kk < 5; ++kk){
          float rs = 0.f;
          for (int v = 0; v < 17; ++v) rs += A1[kk*289 + v*17 + w];
          beff += b1[kk*16 + c] * rs;
        }
        float s = g1[tid] * rsqrtf(v1[tid] + 1e-5f);
        bias1f[tid] = s * (beff - m1[tid]) + be1[tid];
      } else if (tid < 368){
        int cw = tid - 272;
        int c = cw / 6, w = cw - c * 6;
        float beff = 0.f;
        for (int kk = 0; kk < 5; ++kk){
          float rs = 0.f;
          for (int v = 0; v < 6; ++v) rs += A2[kk*36 + v*6 + w];
          beff += b2[kk*16 + c] * rs;
        }
        float s = g2[cw] * rsqrtf(v2[cw] + 1e-5f);
        bias2f[cw] = s * (beff - m2[cw]) + be2[cw];
      } else if (tid < 384){
        int o = tid - 368;
        float s = g3[o] * rsqrtf(v3[o] + 1e-5f);
        bias3f[o] = s * (b3[o] - m3[o]) + be3[o];
      } else if (tid < 448){
        int o = tid - 384;
        float s = g4[o] * rsqrtf(v4[o] + 1e-5f);
        bias4f[o] = s * (b4[o] - m4[o]) + be4[o];
      }
    }
  }
}

// ---- big GEMM (stages 1,2): block = 64 t, NW waves. Wave h covers M-tiles
// h*NM..h*NM+NM-1 x ALL 4 n-tiles (T_w=64). A from global in fragment order
// (1024B coalesced per load), B from LDS patch. Distance-1 double buffer.
template<int MT, int NW, int NM, int KSTEPS, int RD, int PITCH, int SRC_R, bool IN_F32>
__launch_bounds__(NW*64)
__global__ void gemm_big(const void* __restrict__ src, const u16* __restrict__ Wf,
                         const float* __restrict__ bias, u16* __restrict__ dst)
{
  constexpr int MTOT = MT * 16;
  constexpr int ROWS = 76;          // 64 + 4 front pad + 8 back halo (+pad-step reads <=72)
  constexpr int NTH = NW * 64;
  __shared__ u16 patch[ROWS * PITCH];
  const int t0 = blockIdx.x * 64;
  const int n  = blockIdx.y;
  const int tid = threadIdx.x;

  if constexpr (IN_F32){
    for (int idx = tid; idx < ROWS * PITCH; idx += NTH){
      int row = idx / PITCH, col = idx - row * PITCH;
      int ts = t0 + row - 4;
      u16 v = 0;
      if (ts >= 0 && ts < T_LEN && col < SRC_R)
        v = f2bf(((const float*)src)[((size_t)n * T_LEN + ts) * SRC_R + col]);
      patch[idx] = v;
    }
  } else {
    constexpr int GP = PITCH / 8;
    for (int idx = tid; idx < ROWS * GP; idx += NTH){
      int row = idx / GP, g = idx - row * GP;
      int ts = t0 + row - 4;
      int col = g * 8;
      u16x8 v = (u16x8)0;
      if (ts >= 0 && ts < T_LEN && col + 8 <= SRC_R)
        v = *reinterpret_cast<const u16x8*>(&((const u16*)src)[((size_t)n * T_LEN + ts) * SRC_R + col]);
      *reinterpret_cast<u16x8*>(&patch[row * PITCH + col]) = v;
    }
  }
  __syncthreads();

  const int lane = tid & 63;
  const int h    = tid >> 6;
  const int q    = lane >> 4;
  const int l15  = lane & 15;

  bool mok[NM];
  const u16* aptr[NM];
#pragma unroll
  for (int i = 0; i < NM; ++i){
    int mt = h * NM + i;
    mok[i] = (mt < MT);
    aptr[i] = Wf + (size_t)(mok[i] ? mt : 0) * 512 + lane * 8;
  }
  const u16* bp[4];
#pragma unroll
  for (int j = 0; j < 4; ++j)
    bp[j] = patch + (j * 16 + l15) * PITCH;

  f32x4 acc[NM][4];
#pragma unroll
  for (int i = 0; i < NM; ++i)
#pragma unroll
    for (int j = 0; j < 4; ++j)
      acc[i][j] = (f32x4){0.f, 0.f, 0.f, 0.f};

  bf16x8 aF[2][NM];
  bf16x8 bF[2][4];

  auto loadA = [&](int buf, int ks){
    const size_t so = (size_t)ks * (MT * 512);
#pragma unroll
    for (int i = 0; i < NM; ++i)
      aF[buf][i] = *reinterpret_cast<const bf16x8*>(aptr[i] + so);
  };
  auto loadB = [&](int buf, int ks){
    const int k0 = ks * 32 + q * 8;
    const int dt = k0 / RD;
    const int r  = k0 - dt * RD;
    const int od = dt * PITCH + r;
#pragma unroll
    for (int j = 0; j < 4; ++j)
      bF[buf][j] = *reinterpret_cast<const bf16x8*>(bp[j] + od);
  };
  auto step = [&](int buf){
#pragma unroll
    for (int i = 0; i < NM; ++i){
      if (!mok[i]) continue;
#pragma unroll
      for (int j = 0; j < 4; ++j)
        acc[i][j] = __builtin_amdgcn_mfma_f32_16x16x32_bf16(aF[buf][i], bF[buf][j], acc[i][j], 0, 0, 0);
    }
  };

  loadA(0, 0); loadB(0, 0);
  for (int ks = 0; ks + 2 <= KSTEPS; ks += 2){   // KSTEPS even
    loadA(1, ks + 1); loadB(1, ks + 1);
    step(0);
    if (ks + 2 < KSTEPS){ loadA(0, ks + 2); loadB(0, ks + 2); }
    step(1);
  }

#pragma unroll
  for (int i = 0; i < NM; ++i){
    if (!mok[i]) continue;
    const int chb = (h * NM + i) * 16 + q * 4;
    const float b0 = bias[chb+0], b1v = bias[chb+1], b2v = bias[chb+2], b3v = bias[chb+3];
#pragma unroll
    for (int j = 0; j < 4; ++j){
      const int t = t0 + j * 16 + l15;
      ushort4 o;
      o.x = f2bf(acc[i][j][0] + b0);
      o.y = f2bf(acc[i][j][1] + b1v);
      o.z = f2bf(acc[i][j][2] + b2v);
      o.w = f2bf(acc[i][j][3] + b3v);
      *reinterpret_cast<ushort4*>(&dst[((size_t)n * T_LEN + t) * MTOT + chb]) = o;
    }
  }
}

// ---- fused stages 3+4: block = 64 t out, 4 waves.
// Stage A: X3 tiles (16ch) for t in [t0-8, t0+72) -> LDS (zero-masked at t bounds).
// Stage B: out[64ch] = leaky(W4f @ X3patch + b4), fp32 out.
__launch_bounds__(256)
__global__ void gemm34(const u16* __restrict__ X2, const u16* __restrict__ W3f,
                       const float* __restrict__ bias3, const u16* __restrict__ W4f,
                       const float* __restrict__ bias4, float* __restrict__ out)
{
  __shared__ u16 patch[86 * 104];   // X2 rows t0-10 .. t0+75
  __shared__ u16 X3L[80 * 16];      // X3 t0-8 .. t0+71, 16 ch
  const int t0 = blockIdx.x * 64;
  const int n  = blockIdx.y;
  const int tid = threadIdx.x;

  for (int idx = tid; idx < 86 * 13; idx += 256){
    int row = idx / 13, g = idx - row * 13;
    int ts = t0 + row - 10;
    int col = g * 8;
    u16x8 v = (u16x8)0;
    if (ts >= 0 && ts < T_LEN && col + 8 <= 96)
      v = *reinterpret_cast<const u16x8*>(&X2[((size_t)n * T_LEN + ts) * 96 + col]);
    *reinterpret_cast<u16x8*>(&patch[row * 104 + col]) = v;
  }
  __syncthreads();

  const int lane = tid & 63;
  const int wv   = tid >> 6;
  const int q    = lane >> 4;
  const int l15  = lane & 15;

  // ---- stage 3: wave wv computes X3 tile j=wv (wave 0 also j=4). 16 ksteps.
  {
    const bool two = (wv == 0);
    f32x4 a0 = (f32x4){0,0,0,0}, a1 = (f32x4){0,0,0,0};
    bf16x8 aF[2], b0F[2], b1F[2];
    const u16* bp0 = patch + (16 * wv + l15) * 104;
    const u16* bp1 = patch + (64 + l15) * 104;
    auto load3 = [&](int buf, int ks){
      const int k0 = ks * 32 + q * 8;
      const int dt = k0 / 96, r = k0 - dt * 96;
      const int od = dt * 104 + r;
      aF[buf]  = *reinterpret_cast<const bf16x8*>(W3f + ks * 512 + lane * 8);
      b0F[buf] = *reinterpret_cast<const bf16x8*>(bp0 + od);
      b1F[buf] = *reinterpret_cast<const bf16x8*>(bp1 + od);
    };
    auto step3 = [&](int buf){
      a0 = __builtin_amdgcn_mfma_f32_16x16x32_bf16(aF[buf], b0F[buf], a0, 0, 0, 0);
      if (two) a1 = __builtin_amdgcn_mfma_f32_16x16x32_bf16(aF[buf], b1F[buf], a1, 0, 0, 0);
    };
    load3(0, 0);
    for (int ks = 0; ks + 2 <= 16; ks += 2){
      load3(1, ks + 1);
      step3(0);
      if (ks + 2 < 16) load3(0, ks + 2);
      step3(1);
    }
    const float c0 = bias3[q*4+0], c1 = bias3[q*4+1], c2 = bias3[q*4+2], c3 = bias3[q*4+3];
    {
      int trow = 16 * wv + l15;
      int t = t0 - 8 + trow;
      float v0 = a0[0]+c0, v1 = a0[1]+c1, v2 = a0[2]+c2, v3 = a0[3]+c3;
      v0 = v0 > 0.f ? v0 : 0.01f*v0; v1 = v1 > 0.f ? v1 : 0.01f*v1;
      v2 = v2 > 0.f ? v2 : 0.01f*v2; v3 = v3 > 0.f ? v3 : 0.01f*v3;
      if (t < 0 || t >= T_LEN){ v0 = v1 = v2 = v3 = 0.f; }
      ushort4 o; o.x = f2bf(v0); o.y = f2bf(v1); o.z = f2bf(v2); o.w = f2bf(v3);
      *reinterpret_cast<ushort4*>(&X3L[trow * 16 + q * 4]) = o;
    }
    if (two){
      int trow = 64 + l15;
      int t = t0 - 8 + trow;
      float v0 = a1[0]+c0, v1 = a1[1]+c1, v2 = a1[2]+c2, v3 = a1[3]+c3;
      v0 = v0 > 0.f ? v0 : 0.01f*v0; v1 = v1 > 0.f ? v1 : 0.01f*v1;
      v2 = v2 > 0.f ? v2 : 0.01f*v2; v3 = v3 > 0.f ? v3 : 0.01f*v3;
      if (t < 0 || t >= T_LEN){ v0 = v1 = v2 = v3 = 0.f; }
      ushort4 o; o.x = f2bf(v0); o.y = f2bf(v1); o.z = f2bf(v2); o.w = f2bf(v3);
      *reinterpret_cast<ushort4*>(&X3L[trow * 16 + q * 4]) = o;
    }
  }
  __syncthreads();

  // ---- stage 4: wave wv = M-tile (16 of 64 ch), 4 n-tiles, 2 ksteps (K=48 pad 64).
  {
    f32x4 acc[4];
#pragma unroll
    for (int j = 0; j < 4; ++j) acc[j] = (f32x4){0,0,0,0};
    bf16x8 aF[2], bF[2][4];
    auto load4 = [&](int buf, int ks){
      const int k0 = ks * 32 + q * 8;
      const int dt2 = k0 >> 4, ch0 = k0 & 15;
      aF[buf] = *reinterpret_cast<const bf16x8*>(W4f + (ks * 4 + wv) * 512 + lane * 8);
#pragma unroll
      for (int j = 0; j < 4; ++j)
        bF[buf][j] = *reinterpret_cast<const bf16x8*>(&X3L[(j * 16 + l15 + dt2 + 7) * 16 + ch0]);
    };
    load4(0, 0); load4(1, 1);
#pragma unroll
    for (int j = 0; j < 4; ++j)
      acc[j] = __builtin_amdgcn_mfma_f32_16x16x32_bf16(aF[0], bF[0][j], acc[j], 0, 0, 0);
#pragma unroll
    for (int j = 0; j < 4; ++j)
      acc[j] = __builtin_amdgcn_mfma_f32_16x16x32_bf16(aF[1], bF[1][j], acc[j], 0, 0, 0);

    const int chb = wv * 16 + q * 4;
    const float c0 = bias4[chb+0], c1 = bias4[chb+1], c2 = bias4[chb+2], c3 = bias4[chb+3];
#pragma unroll
    for (int j = 0; j < 4; ++j){
      const int t = t0 + j * 16 + l15;
      float v0 = acc[j][0]+c0, v1 = acc[j][1]+c1, v2 = acc[j][2]+c2, v3 = acc[j][3]+c3;
      v0 = v0 > 0.f ? v0 : 0.01f*v0; v1 = v1 > 0.f ? v1 : 0.01f*v1;
      v2 = v2 > 0.f ? v2 : 0.01f*v2; v3 = v3 > 0.f ? v3 : 0.01f*v3;
      float4 o; o.x = v0; o.y = v1; o.z = v2; o.w = v3;
      *reinterpret_cast<float4*>(&out[((size_t)n * T_LEN + t) * 64 + chb]) = o;
    }
  }
}

extern "C" void kernel_launch(void* const* d_in, const int* in_sizes, int n_in,
                              void* d_out, int out_size, void* d_ws, size_t ws_size,
                              hipStream_t stream)
{
  const float* poses = (const float*)d_in[0];
  const float* A1  = (const float*)d_in[1];
  const float* A2  = (const float*)d_in[2];
  const float* w1  = (const float*)d_in[3];
  const float* b1  = (const float*)d_in[4];
  const float* g1  = (const float*)d_in[5];
  const float* be1 = (const float*)d_in[6];
  const float* m1  = (const float*)d_in[7];
  const float* v1  = (const float*)d_in[8];
  const float* w2  = (const float*)d_in[9];
  const float* b2  = (const float*)d_in[10];
  const float* g2  = (const float*)d_in[11];
  const float* be2 = (const float*)d_in[12];
  const float* m2  = (const float*)d_in[13];
  const float* v2  = (const float*)d_in[14];
  const float* w3  = (const float*)d_in[15];
  const float* b3  = (const float*)d_in[16];
  const float* g3  = (const float*)d_in[17];
  const float* be3 = (const float*)d_in[18];
  const float* m3  = (const float*)d_in[19];
  const float* v3  = (const float*)d_in[20];
  const float* w4  = (const float*)d_in[21];
  const float* b4  = (const float*)d_in[22];
  const float* g4  = (const float*)d_in[23];
  const float* be4 = (const float*)d_in[24];
  const float* m4  = (const float*)d_in[25];
  const float* v4  = (const float*)d_in[26];

  uint8_t* ws = (uint8_t*)d_ws;
  size_t off = 0;
  auto alloc = [&](size_t bytes) -> void* {
    void* p = ws + off;
    off += (bytes + 255) & ~(size_t)255;
    return p;
  };
  u16* W1f = (u16*)alloc(16 * 17 * 512 * 2);   // 16 ksteps x 17 mt x 512
  u16* W2f = (u16*)alloc(78 * 6 * 512 * 2);    // 78 ksteps x 6 mt x 512
  u16* W3f = (u16*)alloc(16 * 1 * 512 * 2);
  u16* W4f = (u16*)alloc(2 * 4 * 512 * 2);
  float* bias1f = (float*)alloc(272 * 4);
  float* bias2f = (float*)alloc(96 * 4);
  float* bias3f = (float*)alloc(16 * 4);
  float* bias4f = (float*)alloc(64 * 4);
  u16* X1 = (u16*)alloc((size_t)NB * T_LEN * 272 * 2);
  u16* X2 = (u16*)alloc((size_t)NB * T_LEN * 96 * 2);

  hipLaunchKernelGGL(prep_all, dim3(1530), dim3(256), 0, stream,
                     w1, A1, g1, v1, W1f,
                     w2, A2, g2, v2, W2f,
                     w3, g3, v3, W3f,
                     w4, g4, v4, W4f,
                     b1, be1, m1, b2, be2, m2, b3, be3, m3, b4, be4, m4,
                     bias1f, bias2f, bias3f, bias4f);

  dim3 grid(T_LEN / 64, NB);
  // stage1: MT=17, NW=6 waves, NM=3 (R_w=48, T_w=64), K=512 (16 ks), RD=56
  hipLaunchKernelGGL((gemm_big<17, 6, 3, 16, 56, 56, 51, true>), grid, dim3(384), 0, stream,
                     (const void*)poses, W1f, bias1f, X1);
  // stage2: MT=6, NW=3 waves, NM=2 (R_w=32, T_w=64), K=2496 (78 ks), RD=272
  hipLaunchKernelGGL((gemm_big<6, 3, 2, 78, 272, 280, 272, false>), grid, dim3(192), 0, stream,
                     (const void*)X1, W2f, bias2f, X2);
  // fused stages 3+4
  hipLaunchKernelGGL(gemm34, grid, dim3(256), 0, stream, X2, W3f, bias3f, W4f, bias4f, (float*)d_out);
}

// Round 5
// 164.640 us; speedup vs baseline: 1.6113x; 1.0516x over previous
//
#include <hip/hip_runtime.h>
#include <stdint.h>

typedef unsigned short u16;
typedef __attribute__((ext_vector_type(8))) __bf16 bf16x8;
typedef __attribute__((ext_vector_type(8))) u16 u16x8;
typedef __attribute__((ext_vector_type(4))) float f32x4;

#define T_LEN 2048
#define NB 16

__device__ __forceinline__ u16 f2bf(float f){
  uint32_t x = __builtin_bit_cast(uint32_t, f);
  x += 0x7FFFu + ((x >> 16) & 1u);
  return (u16)(x >> 16);
}

// joint -> (body part, index within part, part length)
__constant__ int c_part[17] = {1,2,3,1,1,4,4,5,5,2,2,3,3,0,0,0,0};
__constant__ int c_pidx[17] = {0,0,0,1,2,0,1,0,1,1,2,1,2,0,1,2,3};
__constant__ int c_plen[17] = {3,3,3,3,3,2,2,2,2,3,3,3,3,4,4,4,4};

// ---- all weight folds + biases, ONE launch. Weights in MFMA fragment order:
// fidx = (ks*MT + mt)*512 + lane*8 + j, lane = q*16 + r.
__global__ void prep_all(
  const float* __restrict__ w1, const float* __restrict__ A1, const float* __restrict__ g1, const float* __restrict__ v1, u16* __restrict__ W1f,
  const float* __restrict__ w2, const float* __restrict__ A2, const float* __restrict__ g2, const float* __restrict__ v2, u16* __restrict__ W2f,
  const float* __restrict__ w3, const float* __restrict__ g3, const float* __restrict__ v3, u16* __restrict__ W3f,
  const float* __restrict__ w4, const float* __restrict__ g4, const float* __restrict__ v4, u16* __restrict__ W4f,
  const float* b1, const float* be1, const float* m1,
  const float* b2, const float* be2, const float* m2,
  const float* b3, const float* be3, const float* m3,
  const float* b4, const float* be4, const float* m4,
  float* bias1f, float* bias2f, float* bias3f, float* bias4f)
{
  const int bid = blockIdx.x;
  if (bid < 544){
    // W1f[272][512], k' = dt*56 + u*3 + ci, MT=17, 16 ksteps
    int idx = bid * 256 + threadIdx.x;          // < 139264 exact
    int cw = idx >> 9, kp = idx & 511;
    int c = cw / 17, w = cw - c * 17;
    int dt = kp / 56, r0 = kp - dt * 56;
    float val = 0.f;
    if (dt < 9 && r0 < 51){
      int u = r0 / 3, ci = r0 - u * 3;
      for (int kk = 0; kk < 5; ++kk)
        for (int dv = 0; dv < 5; ++dv){
          int v = u - dv + 2;
          if (v >= 0 && v < 17)
            val += w1[(kk*16 + c)*135 + ci*45 + dt*5 + dv] * A1[kk*289 + v*17 + w];
        }
      val *= g1[cw] * rsqrtf(v1[cw] + 1e-5f);
    }
    int mt = cw >> 4, r = cw & 15, ks = kp >> 5, kq = kp & 31;
    W1f[(ks*17 + mt)*512 + ((kq>>3)*16 + r)*8 + (kq&7)] = f2bf(val);
  } else if (bid < 1480){
    // W2f[96][2496], k' = dt*272 + f*17 + J, MT=6, 78 ksteps (real K=2448)
    int idx = (bid - 544) * 256 + threadIdx.x;  // < 239616 exact
    int cw = idx / 2496, kp = idx - cw * 2496;
    int c = cw / 6, w = cw - c * 6;
    int dt = kp / 272, fj = kp - dt * 272;
    float val = 0.f;
    if (dt < 9){
      int f = fj / 17, J = fj - f * 17;
      int p = c_part[J];
      int ci = f * c_plen[J] + c_pidx[J];
      for (int kk = 0; kk < 5; ++kk)
        for (int dv = 0; dv < 3; ++dv){
          int v = p - dv + 1;
          if (v >= 0 && v < 6)
            val += w2[(kk*16 + c)*1728 + ci*27 + dt*3 + dv] * A2[kk*36 + v*6 + w];
        }
      val *= g2[cw] * rsqrtf(v2[cw] + 1e-5f);
    }
    int mt = cw >> 4, r = cw & 15, ks = kp >> 5, kq = kp & 31;
    W2f[(ks*6 + mt)*512 + ((kq>>3)*16 + r)*8 + (kq&7)] = f2bf(val);
  } else {
    int idx = (bid - 1480) * 256 + threadIdx.x;
    if (idx < 8192){
      // W3f[16][512], k' = dt*96 + ch (dt<5), MT=1, 16 ksteps
      int cw = idx >> 9, kp = idx & 511;
      int dt = kp / 96, ch = kp - dt * 96;
      float val = 0.f;
      if (dt < 5){
        float s = g3[cw] * rsqrtf(v3[cw] + 1e-5f);
        val = s * w3[cw*480 + ch*5 + dt];
      }
      int ks = kp >> 5, kq = kp & 31;
      W3f[ks*512 + ((kq>>3)*16 + cw)*8 + (kq&7)] = f2bf(val);
    } else if (idx < 12288){
      // W4f[64][64], k' = dt*16 + ch (dt<3), MT=4, 2 ksteps
      int i2 = idx - 8192;
      int cw = i2 >> 6, kp = i2 & 63;
      int dt = kp >> 4, ch = kp & 15;
      float val = 0.f;
      if (dt < 3){
        float s = g4[cw] * rsqrtf(v4[cw] + 1e-5f);
        val = s * w4[cw*48 + ch*3 + dt];
      }
      int mt = cw >> 4, r = cw & 15, ks = kp >> 5, kq = kp & 31;
      W4f[(ks*4 + mt)*512 + ((kq>>3)*16 + r)*8 + (kq&7)] = f2bf(val);
    } else if (idx < 12736){
      int tid = idx - 12288;
      if (tid < 272){
        int c = tid / 17, w = tid - c * 17;
        float beff = 0.f;
        for (int kk = 0; kk < 5; ++kk){
          float rs = 0.f;
          for (int v = 0; v < 17; ++v) rs += A1[kk*289 + v*17 + w];
          beff += b1[kk*16 + c] * rs;
        }
        float s = g1[tid] * rsqrtf(v1[tid] + 1e-5f);
        bias1f[tid] = s * (beff - m1[tid]) + be1[tid];
      } else if (tid < 368){
        int cw = tid - 272;
        int c = cw / 6, w = cw - c * 6;
        float beff = 0.f;
        for (int kk = 0; kk < 5; ++kk){
          float rs = 0.f;
          for (int v = 0; v < 6; ++v) rs += A2[kk*36 + v*6 + w];
          beff += b2[kk*16 + c] * rs;
        }
        float s = g2[cw] * rsqrtf(v2[cw] + 1e-5f);
        bias2f[cw] = s * (beff - m2[cw]) + be2[cw];
      } else if (tid < 384){
        int o = tid - 368;
        float s = g3[o] * rsqrtf(v3[o] + 1e-5f);
        bias3f[o] = s * (b3[o] - m3[o]) + be3[o];
      } else if (tid < 448){
        int o = tid - 384;
        float s = g4[o] * rsqrtf(v4[o] + 1e-5f);
        bias4f[o] = s * (b4[o] - m4[o]) + be4[o];
      }
    }
  }
}

// ---- stage 1 GEMM: grid (32,16,2). Block = 64 t, M-chunk z (9 tiles), 3 waves.
// Wave h: M-tiles z*9 + h*3 + i (i<3) x 4 n-tiles. Distance-1 double buffer.
__launch_bounds__(192)
__global__ void gemm_s1(const float* __restrict__ src, const u16* __restrict__ Wf,
                        const float* __restrict__ bias, u16* __restrict__ dst)
{
  constexpr int KSTEPS = 16, RD = 56, PITCH = 56, SRC_R = 51, ROWS = 73, NM = 3;
  __shared__ u16 patch[ROWS * PITCH];
  const int t0 = blockIdx.x * 64;
  const int n  = blockIdx.y;
  const int z  = blockIdx.z;
  const int tid = threadIdx.x;

  for (int idx = tid; idx < ROWS * PITCH; idx += 192){
    int row = idx / PITCH, col = idx - row * PITCH;
    int ts = t0 + row - 4;
    u16 v = 0;
    if (ts >= 0 && ts < T_LEN && col < SRC_R)
      v = f2bf(src[((size_t)n * T_LEN + ts) * SRC_R + col]);
    patch[idx] = v;
  }
  __syncthreads();

  const int lane = tid & 63;
  const int h    = tid >> 6;
  const int q    = lane >> 4;
  const int l15  = lane & 15;

  bool mok[NM];
  const u16* aptr[NM];
#pragma unroll
  for (int i = 0; i < NM; ++i){
    int mt = z * 9 + h * 3 + i;
    mok[i] = (mt < 17);
    aptr[i] = Wf + (size_t)(mok[i] ? mt : 0) * 512 + lane * 8;
  }
  const u16* bp[4];
#pragma unroll
  for (int j = 0; j < 4; ++j)
    bp[j] = patch + (j * 16 + l15) * PITCH;

  f32x4 acc[NM][4];
#pragma unroll
  for (int i = 0; i < NM; ++i)
#pragma unroll
    for (int j = 0; j < 4; ++j)
      acc[i][j] = (f32x4){0.f, 0.f, 0.f, 0.f};

  bf16x8 aF[2][NM];
  bf16x8 bF[2][4];

  auto loadstep = [&](int buf, int ks){
    const size_t so = (size_t)ks * (17 * 512);
#pragma unroll
    for (int i = 0; i < NM; ++i)
      aF[buf][i] = *reinterpret_cast<const bf16x8*>(aptr[i] + so);
    const int k0 = ks * 32 + q * 8;
    const int dt = k0 / RD;
    const int r  = k0 - dt * RD;
    const int od = dt * PITCH + r;
#pragma unroll
    for (int j = 0; j < 4; ++j)
      bF[buf][j] = *reinterpret_cast<const bf16x8*>(bp[j] + od);
  };
  auto step = [&](int buf){
#pragma unroll
    for (int i = 0; i < NM; ++i){
      if (!mok[i]) continue;
#pragma unroll
      for (int j = 0; j < 4; ++j)
        acc[i][j] = __builtin_amdgcn_mfma_f32_16x16x32_bf16(aF[buf][i], bF[buf][j], acc[i][j], 0, 0, 0);
    }
  };

  loadstep(0, 0);
  for (int ks = 0; ks + 2 <= KSTEPS; ks += 2){
    loadstep(1, ks + 1);
    step(0);
    if (ks + 2 < KSTEPS) loadstep(0, ks + 2);
    step(1);
  }

#pragma unroll
  for (int i = 0; i < NM; ++i){
    if (!mok[i]) continue;
    const int chb = (z * 9 + h * 3 + i) * 16 + q * 4;
    const float b0 = bias[chb+0], b1v = bias[chb+1], b2v = bias[chb+2], b3v = bias[chb+3];
#pragma unroll
    for (int j = 0; j < 4; ++j){
      const int t = t0 + j * 16 + l15;
      ushort4 o;
      o.x = f2bf(acc[i][j][0] + b0);
      o.y = f2bf(acc[i][j][1] + b1v);
      o.z = f2bf(acc[i][j][2] + b2v);
      o.w = f2bf(acc[i][j][3] + b3v);
      *reinterpret_cast<ushort4*>(&dst[((size_t)n * T_LEN + t) * 272 + chb]) = o;
    }
  }
}

// ---- stage 2 GEMM: grid (32,16,2). Block = 64 t, M-chunk z (3 tiles), 3 waves.
// Wave h: M-tile z*3 + h x 4 n-tiles (NM=1, 4 MFMA/kstep). Ring-3 prefetch (depth 2).
__launch_bounds__(192)
__global__ void gemm_s2(const u16* __restrict__ src, const u16* __restrict__ Wf,
                        const float* __restrict__ bias, u16* __restrict__ dst)
{
  constexpr int KSTEPS = 78, RD = 272, PITCH = 280, SRC_R = 272, ROWS = 73;
  __shared__ u16 patch[ROWS * PITCH];      // 40880 B -> 4 blocks/CU
  const int t0 = blockIdx.x * 64;
  const int n  = blockIdx.y;
  const int z  = blockIdx.z;
  const int tid = threadIdx.x;

  constexpr int GP = SRC_R / 8;            // 34 groups of 8
  for (int idx = tid; idx < ROWS * GP; idx += 192){
    int row = idx / GP, g = idx - row * GP;
    int ts = t0 + row - 4;
    int col = g * 8;
    u16x8 v = (u16x8)0;
    if (ts >= 0 && ts < T_LEN)
      v = *reinterpret_cast<const u16x8*>(&src[((size_t)n * T_LEN + ts) * SRC_R + col]);
    *reinterpret_cast<u16x8*>(&patch[row * PITCH + col]) = v;
  }
  __syncthreads();

  const int lane = tid & 63;
  const int h    = tid >> 6;
  const int q    = lane >> 4;
  const int l15  = lane & 15;
  const int mt   = z * 3 + h;

  const u16* aptr = Wf + (size_t)mt * 512 + lane * 8;
  const u16* bp[4];
#pragma unroll
  for (int j = 0; j < 4; ++j)
    bp[j] = patch + (j * 16 + l15) * PITCH;

  f32x4 acc[4];
#pragma unroll
  for (int j = 0; j < 4; ++j) acc[j] = (f32x4){0.f, 0.f, 0.f, 0.f};

  bf16x8 aF[3];
  bf16x8 bF[3][4];

  auto loadstep = [&](int buf, int ks){
    aF[buf] = *reinterpret_cast<const bf16x8*>(aptr + (size_t)ks * (6 * 512));
    const int k0 = ks * 32 + q * 8;
    const int dt = k0 / RD;
    const int r  = k0 - dt * RD;
    const int od = dt * PITCH + r;
#pragma unroll
    for (int j = 0; j < 4; ++j)
      bF[buf][j] = *reinterpret_cast<const bf16x8*>(bp[j] + od);
  };
  auto step = [&](int buf){
#pragma unroll
    for (int j = 0; j < 4; ++j)
      acc[j] = __builtin_amdgcn_mfma_f32_16x16x32_bf16(aF[buf], bF[buf][j], acc[j], 0, 0, 0);
  };

  // ring-3: buffer for ks = ks%3 with ks stepping in 3s (78 = 3*26, no tail)
  loadstep(0, 0);
  loadstep(1, 1);
  for (int ks = 0; ks < KSTEPS; ks += 3){
    loadstep(2, ks + 2);
    step(0);
    if (ks + 3 < KSTEPS) loadstep(0, ks + 3);
    step(1);
    if (ks + 4 < KSTEPS) loadstep(1, ks + 4);
    step(2);
  }

  const int chb = mt * 16 + q * 4;
  const float b0 = bias[chb+0], b1v = bias[chb+1], b2v = bias[chb+2], b3v = bias[chb+3];
#pragma unroll
  for (int j = 0; j < 4; ++j){
    const int t = t0 + j * 16 + l15;
    ushort4 o;
    o.x = f2bf(acc[j][0] + b0);
    o.y = f2bf(acc[j][1] + b1v);
    o.z = f2bf(acc[j][2] + b2v);
    o.w = f2bf(acc[j][3] + b3v);
    *reinterpret_cast<ushort4*>(&dst[((size_t)n * T_LEN + t) * 96 + chb]) = o;
  }
}

// ---- fused stages 3+4: grid (64,16). Block = 32 t out, 4 waves.
// Stage A: X3 rows [t0-8, t0+40) (48 rows, waves 0-2) -> LDS, zero-masked at t bounds.
// Stage B: out[64ch] x 32 t = leaky(W4f @ X3patch + b4), waves = M-tiles, fp32 out.
__launch_bounds__(256)
__global__ void gemm34(const u16* __restrict__ X2, const u16* __restrict__ W3f,
                       const float* __restrict__ bias3, const u16* __restrict__ W4f,
                       const float* __restrict__ bias4, float* __restrict__ out)
{
  __shared__ u16 patch[53 * 104];   // X2 rows t0-10 .. t0+42
  __shared__ u16 X3L[48 * 16];      // X3 t0-8 .. t0+39, 16 ch
  const int t0 = blockIdx.x * 32;
  const int n  = blockIdx.y;
  const int tid = threadIdx.x;

  for (int idx = tid; idx < 53 * 12; idx += 256){
    int row = idx / 12, g = idx - row * 12;
    int ts = t0 + row - 10;
    int col = g * 8;
    u16x8 v = (u16x8)0;
    if (ts >= 0 && ts < T_LEN)
      v = *reinterpret_cast<const u16x8*>(&X2[((size_t)n * T_LEN + ts) * 96 + col]);
    *reinterpret_cast<u16x8*>(&patch[row * 104 + col]) = v;
  }
  __syncthreads();

  const int lane = tid & 63;
  const int wv   = tid >> 6;
  const int q    = lane >> 4;
  const int l15  = lane & 15;

  // ---- stage 3: waves 0-2 compute X3 tile wv (16 rows each). 16 ksteps, dbuf-2.
  if (wv < 3){
    f32x4 a0 = (f32x4){0,0,0,0};
    bf16x8 aF[2], bF[2];
    const u16* bp0 = patch + (16 * wv + l15) * 104;
    auto load3 = [&](int buf, int ks){
      const int k0 = ks * 32 + q * 8;
      const int dt = k0 / 96, r = k0 - dt * 96;
      aF[buf] = *reinterpret_cast<const bf16x8*>(W3f + ks * 512 + lane * 8);
      bF[buf] = *reinterpret_cast<const bf16x8*>(bp0 + dt * 104 + r);
    };
    load3(0, 0);
    for (int ks = 0; ks + 2 <= 16; ks += 2){
      load3(1, ks + 1);
      a0 = __builtin_amdgcn_mfma_f32_16x16x32_bf16(aF[0], bF[0], a0, 0, 0, 0);
      if (ks + 2 < 16) load3(0, ks + 2);
      a0 = __builtin_amdgcn_mfma_f32_16x16x32_bf16(aF[1], bF[1], a0, 0, 0, 0);
    }
    const float c0 = bias3[q*4+0], c1 = bias3[q*4+1], c2 = bias3[q*4+2], c3 = bias3[q*4+3];
    int trow = 16 * wv + l15;
    int t = t0 - 8 + trow;
    float v0 = a0[0]+c0, v1 = a0[1]+c1, v2 = a0[2]+c2, v3 = a0[3]+c3;
    v0 = v0 > 0.f ? v0 : 0.01f*v0; v1 = v1 > 0.f ? v1 : 0.01f*v1;
    v2 = v2 > 0.f ? v2 : 0.01f*v2; v3 = v3 > 0.f ? v3 : 0.01f*v3;
    if (t < 0 || t >= T_LEN){ v0 = v1 = v2 = v3 = 0.f; }
    ushort4 o; o.x = f2bf(v0); o.y = f2bf(v1); o.z = f2bf(v2); o.w = f2bf(v3);
    *reinterpret_cast<ushort4*>(&X3L[trow * 16 + q * 4]) = o;
  }
  __syncthreads();

  // ---- stage 4: wave wv = M-tile (16 of 64 ch), 2 n-tiles, 2 ksteps (K=48 pad 64).
  {
    f32x4 acc[2];
#pragma unroll
    for (int j = 0; j < 2; ++j) acc[j] = (f32x4){0,0,0,0};
    bf16x8 aF[2], bF[2][2];
    auto load4 = [&](int buf, int ks){
      const int k0 = ks * 32 + q * 8;
      const int dt2 = k0 >> 4, ch0 = k0 & 15;
      aF[buf] = *reinterpret_cast<const bf16x8*>(W4f + (ks * 4 + wv) * 512 + lane * 8);
#pragma unroll
      for (int j = 0; j < 2; ++j)
        bF[buf][j] = *reinterpret_cast<const bf16x8*>(&X3L[(j * 16 + l15 + dt2 + 7) * 16 + ch0]);
    };
    load4(0, 0); load4(1, 1);
#pragma unroll
    for (int j = 0; j < 2; ++j)
      acc[j] = __builtin_amdgcn_mfma_f32_16x16x32_bf16(aF[0], bF[0][j], acc[j], 0, 0, 0);
#pragma unroll
    for (int j = 0; j < 2; ++j)
      acc[j] = __builtin_amdgcn_mfma_f32_16x16x32_bf16(aF[1], bF[1][j], acc[j], 0, 0, 0);

    const int chb = wv * 16 + q * 4;
    const float c0 = bias4[chb+0], c1 = bias4[chb+1], c2 = bias4[chb+2], c3 = bias4[chb+3];
#pragma unroll
    for (int j = 0; j < 2; ++j){
      const int t = t0 + j * 16 + l15;
      float v0 = acc[j][0]+c0, v1 = acc[j][1]+c1, v2 = acc[j][2]+c2, v3 = acc[j][3]+c3;
      v0 = v0 > 0.f ? v0 : 0.01f*v0; v1 = v1 > 0.f ? v1 : 0.01f*v1;
      v2 = v2 > 0.f ? v2 : 0.01f*v2; v3 = v3 > 0.f ? v3 : 0.01f*v3;
      float4 o; o.x = v0; o.y = v1; o.z = v2; o.w = v3;
      *reinterpret_cast<float4*>(&out[((size_t)n * T_LEN + t) * 64 + chb]) = o;
    }
  }
}

extern "C" void kernel_launch(void* const* d_in, const int* in_sizes, int n_in,
                              void* d_out, int out_size, void* d_ws, size_t ws_size,
                              hipStream_t stream)
{
  const float* poses = (const float*)d_in[0];
  const float* A1  = (const float*)d_in[1];
  const float* A2  = (const float*)d_in[2];
  const float* w1  = (const float*)d_in[3];
  const float* b1  = (const float*)d_in[4];
  const float* g1  = (const float*)d_in[5];
  const float* be1 = (const float*)d_in[6];
  const float* m1  = (const float*)d_in[7];
  const float* v1  = (const float*)d_in[8];
  const float* w2  = (const float*)d_in[9];
  const float* b2  = (const float*)d_in[10];
  const float* g2  = (const float*)d_in[11];
  const float* be2 = (const float*)d_in[12];
  const float* m2  = (const float*)d_in[13];
  const float* v2  = (const float*)d_in[14];
  const float* w3  = (const float*)d_in[15];
  const float* b3  = (const float*)d_in[16];
  const float* g3  = (const float*)d_in[17];
  const float* be3 = (const float*)d_in[18];
  const float* m3  = (const float*)d_in[19];
  const float* v3  = (const float*)d_in[20];
  const float* w4  = (const float*)d_in[21];
  const float* b4  = (const float*)d_in[22];
  const float* g4  = (const float*)d_in[23];
  const float* be4 = (const float*)d_in[24];
  const float* m4  = (const float*)d_in[25];
  const float* v4  = (const float*)d_in[26];

  uint8_t* ws = (uint8_t*)d_ws;
  size_t off = 0;
  auto alloc = [&](size_t bytes) -> void* {
    void* p = ws + off;
    off += (bytes + 255) & ~(size_t)255;
    return p;
  };
  u16* W1f = (u16*)alloc(16 * 17 * 512 * 2);
  u16* W2f = (u16*)alloc(78 * 6 * 512 * 2);
  u16* W3f = (u16*)alloc(16 * 1 * 512 * 2);
  u16* W4f = (u16*)alloc(2 * 4 * 512 * 2);
  float* bias1f = (float*)alloc(272 * 4);
  float* bias2f = (float*)alloc(96 * 4);
  float* bias3f = (float*)alloc(16 * 4);
  float* bias4f = (float*)alloc(64 * 4);
  u16* X1 = (u16*)alloc((size_t)NB * T_LEN * 272 * 2);
  u16* X2 = (u16*)alloc((size_t)NB * T_LEN * 96 * 2);

  hipLaunchKernelGGL(prep_all, dim3(1530), dim3(256), 0, stream,
                     w1, A1, g1, v1, W1f,
                     w2, A2, g2, v2, W2f,
                     w3, g3, v3, W3f,
                     w4, g4, v4, W4f,
                     b1, be1, m1, b2, be2, m2, b3, be3, m3, b4, be4, m4,
                     bias1f, bias2f, bias3f, bias4f);

  hipLaunchKernelGGL(gemm_s1, dim3(32, 16, 2), dim3(192), 0, stream, poses, W1f, bias1f, X1);
  hipLaunchKernelGGL(gemm_s2, dim3(32, 16, 2), dim3(192), 0, stream, X1, W2f, bias2f, X2);
  hipLaunchKernelGGL(gemm34, dim3(64, 16), dim3(256), 0, stream, X2, W3f, bias3f, W4f, bias4f, (float*)d_out);
}

// Round 6
// 163.716 us; speedup vs baseline: 1.6204x; 1.0056x over previous
//
#include <hip/hip_runtime.h>
#include <stdint.h>

typedef unsigned short u16;
typedef __attribute__((ext_vector_type(8))) __bf16 bf16x8;
typedef __attribute__((ext_vector_type(8))) u16 u16x8;
typedef __attribute__((ext_vector_type(4))) float f32x4;

#define T_LEN 2048
#define NB 16

__device__ __forceinline__ u16 f2bf(float f){
  uint32_t x = __builtin_bit_cast(uint32_t, f);
  x += 0x7FFFu + ((x >> 16) & 1u);
  return (u16)(x >> 16);
}

// joint -> (body part, index within part, part length)
__constant__ int c_part[17] = {1,2,3,1,1,4,4,5,5,2,2,3,3,0,0,0,0};
__constant__ int c_pidx[17] = {0,0,0,1,2,0,1,0,1,1,2,1,2,0,1,2,3};
__constant__ int c_plen[17] = {3,3,3,3,3,2,2,2,2,3,3,3,3,4,4,4,4};

// ---- all weight folds + biases, ONE launch. Weights in MFMA fragment order:
// fidx = (ks*MT + mt)*512 + lane*8 + j, lane = q*16 + r.
__global__ void prep_all(
  const float* __restrict__ w1, const float* __restrict__ A1, const float* __restrict__ g1, const float* __restrict__ v1, u16* __restrict__ W1f,
  const float* __restrict__ w2, const float* __restrict__ A2, const float* __restrict__ g2, const float* __restrict__ v2, u16* __restrict__ W2f,
  const float* __restrict__ w3, const float* __restrict__ g3, const float* __restrict__ v3, u16* __restrict__ W3f,
  const float* __restrict__ w4, const float* __restrict__ g4, const float* __restrict__ v4, u16* __restrict__ W4f,
  const float* b1, const float* be1, const float* m1,
  const float* b2, const float* be2, const float* m2,
  const float* b3, const float* be3, const float* m3,
  const float* b4, const float* be4, const float* m4,
  float* bias1f, float* bias2f, float* bias3f, float* bias4f)
{
  const int bid = blockIdx.x;
  if (bid < 544){
    // W1f[272][512], k' = dt*56 + u*3 + ci, MT=17, 16 ksteps
    int idx = bid * 256 + threadIdx.x;          // < 139264 exact
    int cw = idx >> 9, kp = idx & 511;
    int c = cw / 17, w = cw - c * 17;
    int dt = kp / 56, r0 = kp - dt * 56;
    float val = 0.f;
    if (dt < 9 && r0 < 51){
      int u = r0 / 3, ci = r0 - u * 3;
      for (int kk = 0; kk < 5; ++kk)
        for (int dv = 0; dv < 5; ++dv){
          int v = u - dv + 2;
          if (v >= 0 && v < 17)
            val += w1[(kk*16 + c)*135 + ci*45 + dt*5 + dv] * A1[kk*289 + v*17 + w];
        }
      val *= g1[cw] * rsqrtf(v1[cw] + 1e-5f);
    }
    int mt = cw >> 4, r = cw & 15, ks = kp >> 5, kq = kp & 31;
    W1f[(ks*17 + mt)*512 + ((kq>>3)*16 + r)*8 + (kq&7)] = f2bf(val);
  } else if (bid < 1480){
    // W2f[96][2496], k' = dt*272 + f*17 + J, MT=6, 78 ksteps (real K=2448)
    int idx = (bid - 544) * 256 + threadIdx.x;  // < 239616 exact
    int cw = idx / 2496, kp = idx - cw * 2496;
    int c = cw / 6, w = cw - c * 6;
    int dt = kp / 272, fj = kp - dt * 272;
    float val = 0.f;
    if (dt < 9){
      int f = fj / 17, J = fj - f * 17;
      int p = c_part[J];
      int ci = f * c_plen[J] + c_pidx[J];
      for (int kk = 0; kk < 5; ++kk)
        for (int dv = 0; dv < 3; ++dv){
          int v = p - dv + 1;
          if (v >= 0 && v < 6)
            val += w2[(kk*16 + c)*1728 + ci*27 + dt*3 + dv] * A2[kk*36 + v*6 + w];
        }
      val *= g2[cw] * rsqrtf(v2[cw] + 1e-5f);
    }
    int mt = cw >> 4, r = cw & 15, ks = kp >> 5, kq = kp & 31;
    W2f[(ks*6 + mt)*512 + ((kq>>3)*16 + r)*8 + (kq&7)] = f2bf(val);
  } else {
    int idx = (bid - 1480) * 256 + threadIdx.x;
    if (idx < 8192){
      // W3f[16][512], k' = dt*96 + ch (dt<5), MT=1, 16 ksteps
      int cw = idx >> 9, kp = idx & 511;
      int dt = kp / 96, ch = kp - dt * 96;
      float val = 0.f;
      if (dt < 5){
        float s = g3[cw] * rsqrtf(v3[cw] + 1e-5f);
        val = s * w3[cw*480 + ch*5 + dt];
      }
      int ks = kp >> 5, kq = kp & 31;
      W3f[ks*512 + ((kq>>3)*16 + cw)*8 + (kq&7)] = f2bf(val);
    } else if (idx < 12288){
      // W4f[64][64], k' = dt*16 + ch (dt<3), MT=4, 2 ksteps
      int i2 = idx - 8192;
      int cw = i2 >> 6, kp = i2 & 63;
      int dt = kp >> 4, ch = kp & 15;
      float val = 0.f;
      if (dt < 3){
        float s = g4[cw] * rsqrtf(v4[cw] + 1e-5f);
        val = s * w4[cw*48 + ch*3 + dt];
      }
      int mt = cw >> 4, r = cw & 15, ks = kp >> 5, kq = kp & 31;
      W4f[(ks*4 + mt)*512 + ((kq>>3)*16 + r)*8 + (kq&7)] = f2bf(val);
    } else if (idx < 12736){
      int tid = idx - 12288;
      if (tid < 272){
        int c = tid / 17, w = tid - c * 17;
        float beff = 0.f;
        for (int kk = 0; kk < 5; ++kk){
          float rs = 0.f;
          for (int v = 0; v < 17; ++v) rs += A1[kk*289 + v*17 + w];
          beff += b1[kk*16 + c] * rs;
        }
        float s = g1[tid] * rsqrtf(v1[tid] + 1e-5f);
        bias1f[tid] = s * (beff - m1[tid]) + be1[tid];
      } else if (tid < 368){
        int cw = tid - 272;
        int c = cw / 6, w = cw - c * 6;
        float beff = 0.f;
        for (int kk = 0; kk < 5; ++kk){
          float rs = 0.f;
          for (int v = 0; v < 6; ++v) rs += A2[kk*36 + v*6 + w];
          beff += b2[kk*16 + c] * rs;
        }
        float s = g2[cw] * rsqrtf(v2[cw] + 1e-5f);
        bias2f[cw] = s * (beff - m2[cw]) + be2[cw];
      } else if (tid < 384){
        int o = tid - 368;
        float s = g3[o] * rsqrtf(v3[o] + 1e-5f);
        bias3f[o] = s * (b3[o] - m3[o]) + be3[o];
      } else if (tid < 448){
        int o = tid - 384;
        float s = g4[o] * rsqrtf(v4[o] + 1e-5f);
        bias4f[o] = s * (b4[o] - m4[o]) + be4[o];
      }
    }
  }
}

// ---- stage 1 GEMM: grid (32,16,2). Block = 64 t, M-chunk z (9 tiles), 3 waves.
// Wave h: M-tiles z*9 + h*3 + i (i<3) x 4 n-tiles. Distance-1 double buffer.
__launch_bounds__(192)
__global__ void gemm_s1(const float* __restrict__ src, const u16* __restrict__ Wf,
                        const float* __restrict__ bias, u16* __restrict__ dst)
{
  constexpr int KSTEPS = 16, RD = 56, PITCH = 56, SRC_R = 51, ROWS = 73, NM = 3;
  __shared__ u16 patch[ROWS * PITCH];
  const int t0 = blockIdx.x * 64;
  const int n  = blockIdx.y;
  const int z  = blockIdx.z;
  const int tid = threadIdx.x;

  for (int idx = tid; idx < ROWS * PITCH; idx += 192){
    int row = idx / PITCH, col = idx - row * PITCH;
    int ts = t0 + row - 4;
    u16 v = 0;
    if (ts >= 0 && ts < T_LEN && col < SRC_R)
      v = f2bf(src[((size_t)n * T_LEN + ts) * SRC_R + col]);
    patch[idx] = v;
  }
  __syncthreads();

  const int lane = tid & 63;
  const int h    = tid >> 6;
  const int q    = lane >> 4;
  const int l15  = lane & 15;

  bool mok[NM];
  const u16* aptr[NM];
#pragma unroll
  for (int i = 0; i < NM; ++i){
    int mt = z * 9 + h * 3 + i;
    mok[i] = (mt < 17);
    aptr[i] = Wf + (size_t)(mok[i] ? mt : 0) * 512 + lane * 8;
  }
  const u16* bp[4];
#pragma unroll
  for (int j = 0; j < 4; ++j)
    bp[j] = patch + (j * 16 + l15) * PITCH;

  f32x4 acc[NM][4];
#pragma unroll
  for (int i = 0; i < NM; ++i)
#pragma unroll
    for (int j = 0; j < 4; ++j)
      acc[i][j] = (f32x4){0.f, 0.f, 0.f, 0.f};

  bf16x8 aF[2][NM];
  bf16x8 bF[2][4];

  auto loadstep = [&](int buf, int ks){
    const size_t so = (size_t)ks * (17 * 512);
#pragma unroll
    for (int i = 0; i < NM; ++i)
      aF[buf][i] = *reinterpret_cast<const bf16x8*>(aptr[i] + so);
    const int k0 = ks * 32 + q * 8;
    const int dt = k0 / RD;
    const int r  = k0 - dt * RD;
    const int od = dt * PITCH + r;
#pragma unroll
    for (int j = 0; j < 4; ++j)
      bF[buf][j] = *reinterpret_cast<const bf16x8*>(bp[j] + od);
  };
  auto step = [&](int buf){
#pragma unroll
    for (int i = 0; i < NM; ++i){
      if (!mok[i]) continue;
#pragma unroll
      for (int j = 0; j < 4; ++j)
        acc[i][j] = __builtin_amdgcn_mfma_f32_16x16x32_bf16(aF[buf][i], bF[buf][j], acc[i][j], 0, 0, 0);
    }
  };

  loadstep(0, 0);
  for (int ks = 0; ks + 2 <= KSTEPS; ks += 2){
    loadstep(1, ks + 1);
    step(0);
    if (ks + 2 < KSTEPS) loadstep(0, ks + 2);
    step(1);
  }

#pragma unroll
  for (int i = 0; i < NM; ++i){
    if (!mok[i]) continue;
    const int chb = (z * 9 + h * 3 + i) * 16 + q * 4;
    const float b0 = bias[chb+0], b1v = bias[chb+1], b2v = bias[chb+2], b3v = bias[chb+3];
#pragma unroll
    for (int j = 0; j < 4; ++j){
      const int t = t0 + j * 16 + l15;
      ushort4 o;
      o.x = f2bf(acc[i][j][0] + b0);
      o.y = f2bf(acc[i][j][1] + b1v);
      o.z = f2bf(acc[i][j][2] + b2v);
      o.w = f2bf(acc[i][j][3] + b3v);
      *reinterpret_cast<ushort4*>(&dst[((size_t)n * T_LEN + t) * 272 + chb]) = o;
    }
  }
}

// ---- stage 2 GEMM: grid (32,16). Block = 64 t, 3 waves.
// Wave h: M-tiles {h, h+3} (NM=2, R_w=32) x 4 n-tiles (T_w=64). 8 MFMA/kstep.
// Ring-3 (distance-2) prefetch, 78 ksteps = 24*3 + tail 3.
__launch_bounds__(192)
__global__ void gemm_s2(const u16* __restrict__ src, const u16* __restrict__ Wf,
                        const float* __restrict__ bias, u16* __restrict__ dst)
{
  constexpr int KSTEPS = 78, RD = 272, PITCH = 280, SRC_R = 272, ROWS = 73;
  __shared__ u16 patch[ROWS * PITCH];      // 40880 B
  const int t0 = blockIdx.x * 64;
  const int n  = blockIdx.y;
  const int tid = threadIdx.x;

  constexpr int GP = SRC_R / 8;            // 34 groups of 8
  for (int idx = tid; idx < ROWS * GP; idx += 192){
    int row = idx / GP, g = idx - row * GP;
    int ts = t0 + row - 4;
    int col = g * 8;
    u16x8 v = (u16x8)0;
    if (ts >= 0 && ts < T_LEN)
      v = *reinterpret_cast<const u16x8*>(&src[((size_t)n * T_LEN + ts) * SRC_R + col]);
    *reinterpret_cast<u16x8*>(&patch[row * PITCH + col]) = v;
  }
  __syncthreads();

  const int lane = tid & 63;
  const int h    = tid >> 6;
  const int q    = lane >> 4;
  const int l15  = lane & 15;

  const u16* aptr0 = Wf + (size_t)h * 512 + lane * 8;          // mt = h
  const u16* aptr1 = aptr0 + 3 * 512;                          // mt = h+3
  const u16* bp[4];
#pragma unroll
  for (int j = 0; j < 4; ++j)
    bp[j] = patch + (j * 16 + l15) * PITCH;

  f32x4 acc[2][4];
#pragma unroll
  for (int i = 0; i < 2; ++i)
#pragma unroll
    for (int j = 0; j < 4; ++j)
      acc[i][j] = (f32x4){0.f, 0.f, 0.f, 0.f};

  bf16x8 aF[3][2];
  bf16x8 bF[3][4];

  auto loadstep = [&](int buf, int ks){
    const size_t so = (size_t)ks * (6 * 512);
    aF[buf][0] = *reinterpret_cast<const bf16x8*>(aptr0 + so);
    aF[buf][1] = *reinterpret_cast<const bf16x8*>(aptr1 + so);
    const int k0 = ks * 32 + q * 8;
    const int dt = k0 / RD;
    const int r  = k0 - dt * RD;
    const int od = dt * PITCH + r;
#pragma unroll
    for (int j = 0; j < 4; ++j)
      bF[buf][j] = *reinterpret_cast<const bf16x8*>(bp[j] + od);
  };
  auto step = [&](int buf){
#pragma unroll
    for (int i = 0; i < 2; ++i)
#pragma unroll
      for (int j = 0; j < 4; ++j)
        acc[i][j] = __builtin_amdgcn_mfma_f32_16x16x32_bf16(aF[buf][i], bF[buf][j], acc[i][j], 0, 0, 0);
  };

  loadstep(0, 0);
  loadstep(1, 1);
  int ks = 0;
  for (; ks < KSTEPS - 3; ks += 3){
    loadstep(2, ks + 2); step(0);
    loadstep(0, ks + 3); step(1);
    loadstep(1, ks + 4); step(2);
  }
  loadstep(2, KSTEPS - 1);
  step(0); step(1); step(2);

#pragma unroll
  for (int i = 0; i < 2; ++i){
    const int chb = (h + i * 3) * 16 + q * 4;
    const float b0 = bias[chb+0], b1v = bias[chb+1], b2v = bias[chb+2], b3v = bias[chb+3];
#pragma unroll
    for (int j = 0; j < 4; ++j){
      const int t = t0 + j * 16 + l15;
      ushort4 o;
      o.x = f2bf(acc[i][j][0] + b0);
      o.y = f2bf(acc[i][j][1] + b1v);
      o.z = f2bf(acc[i][j][2] + b2v);
      o.w = f2bf(acc[i][j][3] + b3v);
      *reinterpret_cast<ushort4*>(&dst[((size_t)n * T_LEN + t) * 96 + chb]) = o;
    }
  }
}

// ---- fused stages 3+4: grid (64,16). Block = 32 t out, 4 waves.
// Stage A: X3 rows [t0-8, t0+40) (48 rows, waves 0-2) -> LDS, zero-masked at t bounds.
// Stage B: out[64ch] x 32 t = leaky(W4f @ X3patch + b4), waves = M-tiles, fp32 out.
__launch_bounds__(256)
__global__ void gemm34(const u16* __restrict__ X2, const u16* __restrict__ W3f,
                       const float* __restrict__ bias3, const u16* __restrict__ W4f,
                       const float* __restrict__ bias4, float* __restrict__ out)
{
  __shared__ u16 patch[53 * 104];   // X2 rows t0-10 .. t0+42
  __shared__ u16 X3L[48 * 16];      // X3 t0-8 .. t0+39, 16 ch
  const int t0 = blockIdx.x * 32;
  const int n  = blockIdx.y;
  const int tid = threadIdx.x;

  for (int idx = tid; idx < 53 * 12; idx += 256){
    int row = idx / 12, g = idx - row * 12;
    int ts = t0 + row - 10;
    int col = g * 8;
    u16x8 v = (u16x8)0;
    if (ts >= 0 && ts < T_LEN)
      v = *reinterpret_cast<const u16x8*>(&X2[((size_t)n * T_LEN + ts) * 96 + col]);
    *reinterpret_cast<u16x8*>(&patch[row * 104 + col]) = v;
  }
  __syncthreads();

  const int lane = tid & 63;
  const int wv   = tid >> 6;
  const int q    = lane >> 4;
  const int l15  = lane & 15;

  // ---- stage 3: waves 0-2 compute X3 tile wv (16 rows each). 16 ksteps, dbuf-2.
  if (wv < 3){
    f32x4 a0 = (f32x4){0,0,0,0};
    bf16x8 aF[2], bF[2];
    const u16* bp0 = patch + (16 * wv + l15) * 104;
    auto load3 = [&](int buf, int ks){
      const int k0 = ks * 32 + q * 8;
      const int dt = k0 / 96, r = k0 - dt * 96;
      aF[buf] = *reinterpret_cast<const bf16x8*>(W3f + ks * 512 + lane * 8);
      bF[buf] = *reinterpret_cast<const bf16x8*>(bp0 + dt * 104 + r);
    };
    load3(0, 0);
    for (int ks = 0; ks + 2 <= 16; ks += 2){
      load3(1, ks + 1);
      a0 = __builtin_amdgcn_mfma_f32_16x16x32_bf16(aF[0], bF[0], a0, 0, 0, 0);
      if (ks + 2 < 16) load3(0, ks + 2);
      a0 = __builtin_amdgcn_mfma_f32_16x16x32_bf16(aF[1], bF[1], a0, 0, 0, 0);
    }
    const float c0 = bias3[q*4+0], c1 = bias3[q*4+1], c2 = bias3[q*4+2], c3 = bias3[q*4+3];
    int trow = 16 * wv + l15;
    int t = t0 - 8 + trow;
    float v0 = a0[0]+c0, v1 = a0[1]+c1, v2 = a0[2]+c2, v3 = a0[3]+c3;
    v0 = v0 > 0.f ? v0 : 0.01f*v0; v1 = v1 > 0.f ? v1 : 0.01f*v1;
    v2 = v2 > 0.f ? v2 : 0.01f*v2; v3 = v3 > 0.f ? v3 : 0.01f*v3;
    if (t < 0 || t >= T_LEN){ v0 = v1 = v2 = v3 = 0.f; }
    ushort4 o; o.x = f2bf(v0); o.y = f2bf(v1); o.z = f2bf(v2); o.w = f2bf(v3);
    *reinterpret_cast<ushort4*>(&X3L[trow * 16 + q * 4]) = o;
  }
  __syncthreads();

  // ---- stage 4: wave wv = M-tile (16 of 64 ch), 2 n-tiles, 2 ksteps (K=48 pad 64).
  {
    f32x4 acc[2];
#pragma unroll
    for (int j = 0; j < 2; ++j) acc[j] = (f32x4){0,0,0,0};
    bf16x8 aF[2], bF[2][2];
    auto load4 = [&](int buf, int ks){
      const int k0 = ks * 32 + q * 8;
      const int dt2 = k0 >> 4, ch0 = k0 & 15;
      aF[buf] = *reinterpret_cast<const bf16x8*>(W4f + (ks * 4 + wv) * 512 + lane * 8);
#pragma unroll
      for (int j = 0; j < 2; ++j)
        bF[buf][j] = *reinterpret_cast<const bf16x8*>(&X3L[(j * 16 + l15 + dt2 + 7) * 16 + ch0]);
    };
    load4(0, 0); load4(1, 1);
#pragma unroll
    for (int j = 0; j < 2; ++j)
      acc[j] = __builtin_amdgcn_mfma_f32_16x16x32_bf16(aF[0], bF[0][j], acc[j], 0, 0, 0);
#pragma unroll
    for (int j = 0; j < 2; ++j)
      acc[j] = __builtin_amdgcn_mfma_f32_16x16x32_bf16(aF[1], bF[1][j], acc[j], 0, 0, 0);

    const int chb = wv * 16 + q * 4;
    const float c0 = bias4[chb+0], c1 = bias4[chb+1], c2 = bias4[chb+2], c3 = bias4[chb+3];
#pragma unroll
    for (int j = 0; j < 2; ++j){
      const int t = t0 + j * 16 + l15;
      float v0 = acc[j][0]+c0, v1 = acc[j][1]+c1, v2 = acc[j][2]+c2, v3 = acc[j][3]+c3;
      v0 = v0 > 0.f ? v0 : 0.01f*v0; v1 = v1 > 0.f ? v1 : 0.01f*v1;
      v2 = v2 > 0.f ? v2 : 0.01f*v2; v3 = v3 > 0.f ? v3 : 0.01f*v3;
      float4 o; o.x = v0; o.y = v1; o.z = v2; o.w = v3;
      *reinterpret_cast<float4*>(&out[((size_t)n * T_LEN + t) * 64 + chb]) = o;
    }
  }
}

extern "C" void kernel_launch(void* const* d_in, const int* in_sizes, int n_in,
                              void* d_out, int out_size, void* d_ws, size_t ws_size,
                              hipStream_t stream)
{
  const float* poses = (const float*)d_in[0];
  const float* A1  = (const float*)d_in[1];
  const float* A2  = (const float*)d_in[2];
  const float* w1  = (const float*)d_in[3];
  const float* b1  = (const float*)d_in[4];
  const float* g1  = (const float*)d_in[5];
  const float* be1 = (const float*)d_in[6];
  const float* m1  = (const float*)d_in[7];
  const float* v1  = (const float*)d_in[8];
  const float* w2  = (const float*)d_in[9];
  const float* b2  = (const float*)d_in[10];
  const float* g2  = (const float*)d_in[11];
  const float* be2 = (const float*)d_in[12];
  const float* m2  = (const float*)d_in[13];
  const float* v2  = (const float*)d_in[14];
  const float* w3  = (const float*)d_in[15];
  const float* b3  = (const float*)d_in[16];
  const float* g3  = (const float*)d_in[17];
  const float* be3 = (const float*)d_in[18];
  const float* m3  = (const float*)d_in[19];
  const float* v3  = (const float*)d_in[20];
  const float* w4  = (const float*)d_in[21];
  const float* b4  = (const float*)d_in[22];
  const float* g4  = (const float*)d_in[23];
  const float* be4 = (const float*)d_in[24];
  const float* m4  = (const float*)d_in[25];
  const float* v4  = (const float*)d_in[26];

  uint8_t* ws = (uint8_t*)d_ws;
  size_t off = 0;
  auto alloc = [&](size_t bytes) -> void* {
    void* p = ws + off;
    off += (bytes + 255) & ~(size_t)255;
    return p;
  };
  u16* W1f = (u16*)alloc(16 * 17 * 512 * 2);
  u16* W2f = (u16*)alloc(78 * 6 * 512 * 2);
  u16* W3f = (u16*)alloc(16 * 1 * 512 * 2);
  u16* W4f = (u16*)alloc(2 * 4 * 512 * 2);
  float* bias1f = (float*)alloc(272 * 4);
  float* bias2f = (float*)alloc(96 * 4);
  float* bias3f = (float*)alloc(16 * 4);
  float* bias4f = (float*)alloc(64 * 4);
  u16* X1 = (u16*)alloc((size_t)NB * T_LEN * 272 * 2);
  u16* X2 = (u16*)alloc((size_t)NB * T_LEN * 96 * 2);

  hipLaunchKernelGGL(prep_all, dim3(1530), dim3(256), 0, stream,
                     w1, A1, g1, v1, W1f,
                     w2, A2, g2, v2, W2f,
                     w3, g3, v3, W3f,
                     w4, g4, v4, W4f,
                     b1, be1, m1, b2, be2, m2, b3, be3, m3, b4, be4, m4,
                     bias1f, bias2f, bias3f, bias4f);

  hipLaunchKernelGGL(gemm_s1, dim3(32, 16, 2), dim3(192), 0, stream, poses, W1f, bias1f, X1);
  hipLaunchKernelGGL(gemm_s2, dim3(32, 16), dim3(192), 0, stream, X1, W2f, bias2f, X2);
  hipLaunchKernelGGL(gemm34, dim3(64, 16), dim3(256), 0, stream, X2, W3f, bias3f, W4f, bias4f, (float*)d_out);
}

// Round 8
// 161.290 us; speedup vs baseline: 1.6448x; 1.0150x over previous
//
#include <hip/hip_runtime.h>
#include <stdint.h>

typedef unsigned short u16;
typedef __attribute__((ext_vector_type(8))) __bf16 bf16x8;
typedef __attribute__((ext_vector_type(8))) u16 u16x8;
typedef __attribute__((ext_vector_type(4))) float f32x4;

#define T_LEN 2048
#define NB 16

__device__ __forceinline__ u16 f2bf(float f){
  uint32_t x = __builtin_bit_cast(uint32_t, f);
  x += 0x7FFFu + ((x >> 16) & 1u);
  return (u16)(x >> 16);
}

// joint -> (body part, index within part, part length)
__constant__ int c_part[17] = {1,2,3,1,1,4,4,5,5,2,2,3,3,0,0,0,0};
__constant__ int c_pidx[17] = {0,0,0,1,2,0,1,0,1,1,2,1,2,0,1,2,3};
__constant__ int c_plen[17] = {3,3,3,3,3,2,2,2,2,3,3,3,3,4,4,4,4};

// ---- poses fp32 [n][t][51] -> bf16 X0 [n][t][56] (cols 51-55 zero) ----
__global__ void conv_poses(const float* __restrict__ poses, u16* __restrict__ X0)
{
  int e = blockIdx.x * 256 + threadIdx.x;          // < 16*2048*56 exact (grid 7168)
  int row = e / 56, c = e - row * 56;
  u16 v = 0;
  if (c < 51) v = f2bf(poses[row * 51 + c]);
  X0[e] = v;
}

// ---- all weight folds + biases, ONE launch. Weights in MFMA fragment order:
// fidx = (ks*MT + mt)*512 + lane*8 + j, lane = q*16 + r.
__global__ void prep_all(
  const float* __restrict__ w1, const float* __restrict__ A1, const float* __restrict__ g1, const float* __restrict__ v1, u16* __restrict__ W1f,
  const float* __restrict__ w2, const float* __restrict__ A2, const float* __restrict__ g2, const float* __restrict__ v2, u16* __restrict__ W2f,
  const float* __restrict__ w3, const float* __restrict__ g3, const float* __restrict__ v3, u16* __restrict__ W3f,
  const float* __restrict__ w4, const float* __restrict__ g4, const float* __restrict__ v4, u16* __restrict__ W4f,
  const float* b1, const float* be1, const float* m1,
  const float* b2, const float* be2, const float* m2,
  const float* b3, const float* be3, const float* m3,
  const float* b4, const float* be4, const float* m4,
  float* bias1f, float* bias2f, float* bias3f, float* bias4f)
{
  const int bid = blockIdx.x;
  if (bid < 544){
    // W1f[272][512], k' = dt*56 + u*3 + ci, MT=17, 16 ksteps
    int idx = bid * 256 + threadIdx.x;          // < 139264 exact
    int cw = idx >> 9, kp = idx & 511;
    int c = cw / 17, w = cw - c * 17;
    int dt = kp / 56, r0 = kp - dt * 56;
    float val = 0.f;
    if (dt < 9 && r0 < 51){
      int u = r0 / 3, ci = r0 - u * 3;
      for (int kk = 0; kk < 5; ++kk)
        for (int dv = 0; dv < 5; ++dv){
          int v = u - dv + 2;
          if (v >= 0 && v < 17)
            val += w1[(kk*16 + c)*135 + ci*45 + dt*5 + dv] * A1[kk*289 + v*17 + w];
        }
      val *= g1[cw] * rsqrtf(v1[cw] + 1e-5f);
    }
    int mt = cw >> 4, r = cw & 15, ks = kp >> 5, kq = kp & 31;
    W1f[(ks*17 + mt)*512 + ((kq>>3)*16 + r)*8 + (kq&7)] = f2bf(val);
  } else if (bid < 1480){
    // W2f[96][2496], k' = dt*272 + f*17 + J, MT=6, 78 ksteps (real K=2448)
    int idx = (bid - 544) * 256 + threadIdx.x;  // < 239616 exact
    int cw = idx / 2496, kp = idx - cw * 2496;
    int c = cw / 6, w = cw - c * 6;
    int dt = kp / 272, fj = kp - dt * 272;
    float val = 0.f;
    if (dt < 9){
      int f = fj / 17, J = fj - f * 17;
      int p = c_part[J];
      int ci = f * c_plen[J] + c_pidx[J];
      for (int kk = 0; kk < 5; ++kk)
        for (int dv = 0; dv < 3; ++dv){
          int v = p - dv + 1;
          if (v >= 0 && v < 6)
            val += w2[(kk*16 + c)*1728 + ci*27 + dt*3 + dv] * A2[kk*36 + v*6 + w];
        }
      val *= g2[cw] * rsqrtf(v2[cw] + 1e-5f);
    }
    int mt = cw >> 4, r = cw & 15, ks = kp >> 5, kq = kp & 31;
    W2f[(ks*6 + mt)*512 + ((kq>>3)*16 + r)*8 + (kq&7)] = f2bf(val);
  } else {
    int idx = (bid - 1480) * 256 + threadIdx.x;
    if (idx < 8192){
      // W3f[16][512], k' = dt*96 + ch (dt<5), MT=1, 16 ksteps
      int cw = idx >> 9, kp = idx & 511;
      int dt = kp / 96, ch = kp - dt * 96;
      float val = 0.f;
      if (dt < 5){
        float s = g3[cw] * rsqrtf(v3[cw] + 1e-5f);
        val = s * w3[cw*480 + ch*5 + dt];
      }
      int ks = kp >> 5, kq = kp & 31;
      W3f[ks*512 + ((kq>>3)*16 + cw)*8 + (kq&7)] = f2bf(val);
    } else if (idx < 12288){
      // W4f[64][64], k' = dt*16 + ch (dt<3), MT=4, 2 ksteps
      int i2 = idx - 8192;
      int cw = i2 >> 6, kp = i2 & 63;
      int dt = kp >> 4, ch = kp & 15;
      float val = 0.f;
      if (dt < 3){
        float s = g4[cw] * rsqrtf(v4[cw] + 1e-5f);
        val = s * w4[cw*48 + ch*3 + dt];
      }
      int mt = cw >> 4, r = cw & 15, ks = kp >> 5, kq = kp & 31;
      W4f[(ks*4 + mt)*512 + ((kq>>3)*16 + r)*8 + (kq&7)] = f2bf(val);
    } else if (idx < 12736){
      int tid = idx - 12288;
      if (tid < 272){
        int c = tid / 17, w = tid - c * 17;
        float beff = 0.f;
        for (int kk = 0; kk < 5; ++kk){
          float rs = 0.f;
          for (int v = 0; v < 17; ++v) rs += A1[kk*289 + v*17 + w];
          beff += b1[kk*16 + c] * rs;
        }
        float s = g1[tid] * rsqrtf(v1[tid] + 1e-5f);
        bias1f[tid] = s * (beff - m1[tid]) + be1[tid];
      } else if (tid < 368){
        int cw = tid - 272;
        int c = cw / 6, w = cw - c * 6;
        float beff = 0.f;
        for (int kk = 0; kk < 5; ++kk){
          float rs = 0.f;
          for (int v = 0; v < 6; ++v) rs += A2[kk*36 + v*6 + w];
          beff += b2[kk*16 + c] * rs;
        }
        float s = g2[cw] * rsqrtf(v2[cw] + 1e-5f);
        bias2f[cw] = s * (beff - m2[cw]) + be2[cw];
      } else if (tid < 384){
        int o = tid - 368;
        float s = g3[o] * rsqrtf(v3[o] + 1e-5f);
        bias3f[o] = s * (b3[o] - m3[o]) + be3[o];
      } else if (tid < 448){
        int o = tid - 384;
        float s = g4[o] * rsqrtf(v4[o] + 1e-5f);
        bias4f[o] = s * (b4[o] - m4[o]) + be4[o];
      }
    }
  }
}

// ---- stage 1 GEMM: grid (32,16,2). Block = 64 t, M-chunk z (9 tiles), 3 waves.
// Wave h: M-tiles z*9 + h*3 + i (i<3) x 4 n-tiles. Distance-1 double buffer.
// Staging: vectorized u16x8 copies from pre-converted bf16 X0 (pitch 56).
// ROWS=73: B-frag reads reach trow = 63 + dt_max(9) = 72 (padding kstep).
__launch_bounds__(192)
__global__ void gemm_s1(const u16* __restrict__ X0, const u16* __restrict__ Wf,
                        const float* __restrict__ bias, u16* __restrict__ dst)
{
  constexpr int KSTEPS = 16, RD = 56, PITCH = 56, ROWS = 73, NM = 3;
  __shared__ u16 patch[ROWS * PITCH];
  const int t0 = blockIdx.x * 64;
  const int n  = blockIdx.y;
  const int z  = blockIdx.z;
  const int tid = threadIdx.x;

  for (int idx = tid; idx < ROWS * 7; idx += 192){
    int row = idx / 7, g = idx - row * 7;
    int ts = t0 + row - 4;
    u16x8 v = (u16x8)0;
    if (ts >= 0 && ts < T_LEN)
      v = *reinterpret_cast<const u16x8*>(&X0[((size_t)n * T_LEN + ts) * 56 + g * 8]);
    *reinterpret_cast<u16x8*>(&patch[row * PITCH + g * 8]) = v;
  }
  __syncthreads();

  const int lane = tid & 63;
  const int h    = tid >> 6;
  const int q    = lane >> 4;
  const int l15  = lane & 15;

  bool mok[NM];
  const u16* aptr[NM];
#pragma unroll
  for (int i = 0; i < NM; ++i){
    int mt = z * 9 + h * 3 + i;
    mok[i] = (mt < 17);
    aptr[i] = Wf + (size_t)(mok[i] ? mt : 0) * 512 + lane * 8;
  }
  const u16* bp[4];
#pragma unroll
  for (int j = 0; j < 4; ++j)
    bp[j] = patch + (j * 16 + l15) * PITCH;

  f32x4 acc[NM][4];
#pragma unroll
  for (int i = 0; i < NM; ++i)
#pragma unroll
    for (int j = 0; j < 4; ++j)
      acc[i][j] = (f32x4){0.f, 0.f, 0.f, 0.f};

  bf16x8 aF[2][NM];
  bf16x8 bF[2][4];

  auto loadstep = [&](int buf, int ks){
    const size_t so = (size_t)ks * (17 * 512);
#pragma unroll
    for (int i = 0; i < NM; ++i)
      aF[buf][i] = *reinterpret_cast<const bf16x8*>(aptr[i] + so);
    const int k0 = ks * 32 + q * 8;
    const int dt = k0 / RD;
    const int r  = k0 - dt * RD;
    const int od = dt * PITCH + r;
#pragma unroll
    for (int j = 0; j < 4; ++j)
      bF[buf][j] = *reinterpret_cast<const bf16x8*>(bp[j] + od);
  };
  auto step = [&](int buf){
#pragma unroll
    for (int i = 0; i < NM; ++i){
      if (!mok[i]) continue;
#pragma unroll
      for (int j = 0; j < 4; ++j)
        acc[i][j] = __builtin_amdgcn_mfma_f32_16x16x32_bf16(aF[buf][i], bF[buf][j], acc[i][j], 0, 0, 0);
    }
  };

  loadstep(0, 0);
  for (int ks = 0; ks + 2 <= KSTEPS; ks += 2){
    loadstep(1, ks + 1);
    step(0);
    if (ks + 2 < KSTEPS) loadstep(0, ks + 2);
    step(1);
  }

#pragma unroll
  for (int i = 0; i < NM; ++i){
    if (!mok[i]) continue;
    const int chb = (z * 9 + h * 3 + i) * 16 + q * 4;
    const float b0 = bias[chb+0], b1v = bias[chb+1], b2v = bias[chb+2], b3v = bias[chb+3];
#pragma unroll
    for (int j = 0; j < 4; ++j){
      const int t = t0 + j * 16 + l15;
      ushort4 o;
      o.x = f2bf(acc[i][j][0] + b0);
      o.y = f2bf(acc[i][j][1] + b1v);
      o.z = f2bf(acc[i][j][2] + b2v);
      o.w = f2bf(acc[i][j][3] + b3v);
      *reinterpret_cast<ushort4*>(&dst[((size_t)n * T_LEN + t) * 272 + chb]) = o;
    }
  }
}

// ---- stage 2 GEMM: grid (32,16). Block = 64 t, 3 waves.
// Wave h: M-tiles {h, h+3} (NM=2, R_w=32) x 4 n-tiles (T_w=64). 8 MFMA/kstep.
// Ring-3 (distance-2) prefetch, 78 ksteps = 25*3 + tail 3.
// ROWS=73 REQUIRED: padding kstep (dt=9) reads trow up to 63+9=72.
__launch_bounds__(192)
__global__ void gemm_s2(const u16* __restrict__ src, const u16* __restrict__ Wf,
                        const float* __restrict__ bias, u16* __restrict__ dst)
{
  constexpr int KSTEPS = 78, RD = 272, PITCH = 280, SRC_R = 272, ROWS = 73;
  __shared__ u16 patch[ROWS * PITCH];      // 40880 B
  const int t0 = blockIdx.x * 64;
  const int n  = blockIdx.y;
  const int tid = threadIdx.x;

  constexpr int GP = SRC_R / 8;            // 34 groups of 8
  for (int idx = tid; idx < ROWS * GP; idx += 192){
    int row = idx / GP, g = idx - row * GP;
    int ts = t0 + row - 4;
    int col = g * 8;
    u16x8 v = (u16x8)0;
    if (ts >= 0 && ts < T_LEN)
      v = *reinterpret_cast<const u16x8*>(&src[((size_t)n * T_LEN + ts) * SRC_R + col]);
    *reinterpret_cast<u16x8*>(&patch[row * PITCH + col]) = v;
  }
  __syncthreads();

  const int lane = tid & 63;
  const int h    = tid >> 6;
  const int q    = lane >> 4;
  const int l15  = lane & 15;

  const u16* aptr0 = Wf + (size_t)h * 512 + lane * 8;          // mt = h
  const u16* aptr1 = aptr0 + 3 * 512;                          // mt = h+3
  const u16* bp[4];
#pragma unroll
  for (int j = 0; j < 4; ++j)
    bp[j] = patch + (j * 16 + l15) * PITCH;

  f32x4 acc[2][4];
#pragma unroll
  for (int i = 0; i < 2; ++i)
#pragma unroll
    for (int j = 0; j < 4; ++j)
      acc[i][j] = (f32x4){0.f, 0.f, 0.f, 0.f};

  bf16x8 aF[3][2];
  bf16x8 bF[3][4];

  auto loadstep = [&](int buf, int ks){
    const size_t so = (size_t)ks * (6 * 512);
    aF[buf][0] = *reinterpret_cast<const bf16x8*>(aptr0 + so);
    aF[buf][1] = *reinterpret_cast<const bf16x8*>(aptr1 + so);
    const int k0 = ks * 32 + q * 8;
    const int dt = k0 / RD;
    const int r  = k0 - dt * RD;
    const int od = dt * PITCH + r;
#pragma unroll
    for (int j = 0; j < 4; ++j)
      bF[buf][j] = *reinterpret_cast<const bf16x8*>(bp[j] + od);
  };
  auto step = [&](int buf){
#pragma unroll
    for (int i = 0; i < 2; ++i)
#pragma unroll
      for (int j = 0; j < 4; ++j)
        acc[i][j] = __builtin_amdgcn_mfma_f32_16x16x32_bf16(aF[buf][i], bF[buf][j], acc[i][j], 0, 0, 0);
  };

  loadstep(0, 0);
  loadstep(1, 1);
  int ks = 0;
  for (; ks < KSTEPS - 3; ks += 3){
    loadstep(2, ks + 2); step(0);
    loadstep(0, ks + 3); step(1);
    loadstep(1, ks + 4); step(2);
  }
  loadstep(2, KSTEPS - 1);
  step(0); step(1); step(2);

#pragma unroll
  for (int i = 0; i < 2; ++i){
    const int chb = (h + i * 3) * 16 + q * 4;
    const float b0 = bias[chb+0], b1v = bias[chb+1], b2v = bias[chb+2], b3v = bias[chb+3];
#pragma unroll
    for (int j = 0; j < 4; ++j){
      const int t = t0 + j * 16 + l15;
      ushort4 o;
      o.x = f2bf(acc[i][j][0] + b0);
      o.y = f2bf(acc[i][j][1] + b1v);
      o.z = f2bf(acc[i][j][2] + b2v);
      o.w = f2bf(acc[i][j][3] + b3v);
      *reinterpret_cast<ushort4*>(&dst[((size_t)n * T_LEN + t) * 96 + chb]) = o;
    }
  }
}

// ---- fused stages 3+4: grid (64,16). Block = 32 t out, 4 waves.
// Stage A: X3 rows [t0-8, t0+40) (48 rows, waves 0-2) -> LDS, zero-masked at t bounds.
// Stage B: out[64ch] x 32 t = leaky(W4f @ X3patch + b4), waves = M-tiles, fp32 out.
__launch_bounds__(256)
__global__ void gemm34(const u16* __restrict__ X2, const u16* __restrict__ W3f,
                       const float* __restrict__ bias3, const u16* __restrict__ W4f,
                       const float* __restrict__ bias4, float* __restrict__ out)
{
  __shared__ u16 patch[53 * 104];   // X2 rows t0-10 .. t0+42
  __shared__ u16 X3L[48 * 16];      // X3 t0-8 .. t0+39, 16 ch
  const int t0 = blockIdx.x * 32;
  const int n  = blockIdx.y;
  const int tid = threadIdx.x;

  for (int idx = tid; idx < 53 * 12; idx += 256){
    int row = idx / 12, g = idx - row * 12;
    int ts = t0 + row - 10;
    int col = g * 8;
    u16x8 v = (u16x8)0;
    if (ts >= 0 && ts < T_LEN)
      v = *reinterpret_cast<const u16x8*>(&X2[((size_t)n * T_LEN + ts) * 96 + col]);
    *reinterpret_cast<u16x8*>(&patch[row * 104 + col]) = v;
  }
  __syncthreads();

  const int lane = tid & 63;
  const int wv   = tid >> 6;
  const int q    = lane >> 4;
  const int l15  = lane & 15;

  // ---- stage 3: waves 0-2 compute X3 tile wv (16 rows each). 16 ksteps, dbuf-2.
  if (wv < 3){
    f32x4 a0 = (f32x4){0,0,0,0};
    bf16x8 aF[2], bF[2];
    const u16* bp0 = patch + (16 * wv + l15) * 104;
    auto load3 = [&](int buf, int ks){
      const int k0 = ks * 32 + q * 8;
      const int dt = k0 / 96, r = k0 - dt * 96;
      aF[buf] = *reinterpret_cast<const bf16x8*>(W3f + ks * 512 + lane * 8);
      bF[buf] = *reinterpret_cast<const bf16x8*>(bp0 + dt * 104 + r);
    };
    load3(0, 0);
    for (int ks = 0; ks + 2 <= 16; ks += 2){
      load3(1, ks + 1);
      a0 = __builtin_amdgcn_mfma_f32_16x16x32_bf16(aF[0], bF[0], a0, 0, 0, 0);
      if (ks + 2 < 16) load3(0, ks + 2);
      a0 = __builtin_amdgcn_mfma_f32_16x16x32_bf16(aF[1], bF[1], a0, 0, 0, 0);
    }
    const float c0 = bias3[q*4+0], c1 = bias3[q*4+1], c2 = bias3[q*4+2], c3 = bias3[q*4+3];
    int trow = 16 * wv + l15;
    int t = t0 - 8 + trow;
    float v0 = a0[0]+c0, v1 = a0[1]+c1, v2 = a0[2]+c2, v3 = a0[3]+c3;
    v0 = v0 > 0.f ? v0 : 0.01f*v0; v1 = v1 > 0.f ? v1 : 0.01f*v1;
    v2 = v2 > 0.f ? v2 : 0.01f*v2; v3 = v3 > 0.f ? v3 : 0.01f*v3;
    if (t < 0 || t >= T_LEN){ v0 = v1 = v2 = v3 = 0.f; }
    ushort4 o; o.x = f2bf(v0); o.y = f2bf(v1); o.z = f2bf(v2); o.w = f2bf(v3);
    *reinterpret_cast<ushort4*>(&X3L[trow * 16 + q * 4]) = o;
  }
  __syncthreads();

  // ---- stage 4: wave wv = M-tile (16 of 64 ch), 2 n-tiles, 2 ksteps (K=48 pad 64).
  {
    f32x4 acc[2];
#pragma unroll
    for (int j = 0; j < 2; ++j) acc[j] = (f32x4){0,0,0,0};
    bf16x8 aF[2], bF[2][2];
    auto load4 = [&](int buf, int ks){
      const int k0 = ks * 32 + q * 8;
      const int dt2 = k0 >> 4, ch0 = k0 & 15;
      aF[buf] = *reinterpret_cast<const bf16x8*>(W4f + (ks * 4 + wv) * 512 + lane * 8);
#pragma unroll
      for (int j = 0; j < 2; ++j)
        bF[buf][j] = *reinterpret_cast<const bf16x8*>(&X3L[(j * 16 + l15 + dt2 + 7) * 16 + ch0]);
    };
    load4(0, 0); load4(1, 1);
#pragma unroll
    for (int j = 0; j < 2; ++j)
      acc[j] = __builtin_amdgcn_mfma_f32_16x16x32_bf16(aF[0], bF[0][j], acc[j], 0, 0, 0);
#pragma unroll
    for (int j = 0; j < 2; ++j)
      acc[j] = __builtin_amdgcn_mfma_f32_16x16x32_bf16(aF[1], bF[1][j], acc[j], 0, 0, 0);

    const int chb = wv * 16 + q * 4;
    const float c0 = bias4[chb+0], c1 = bias4[chb+1], c2 = bias4[chb+2], c3 = bias4[chb+3];
#pragma unroll
    for (int j = 0; j < 2; ++j){
      const int t = t0 + j * 16 + l15;
      float v0 = acc[j][0]+c0, v1 = acc[j][1]+c1, v2 = acc[j][2]+c2, v3 = acc[j][3]+c3;
      v0 = v0 > 0.f ? v0 : 0.01f*v0; v1 = v1 > 0.f ? v1 : 0.01f*v1;
      v2 = v2 > 0.f ? v2 : 0.01f*v2; v3 = v3 > 0.f ? v3 : 0.01f*v3;
      float4 o; o.x = v0; o.y = v1; o.z = v2; o.w = v3;
      *reinterpret_cast<float4*>(&out[((size_t)n * T_LEN + t) * 64 + chb]) = o;
    }
  }
}

extern "C" void kernel_launch(void* const* d_in, const int* in_sizes, int n_in,
                              void* d_out, int out_size, void* d_ws, size_t ws_size,
                              hipStream_t stream)
{
  const float* poses = (const float*)d_in[0];
  const float* A1  = (const float*)d_in[1];
  const float* A2  = (const float*)d_in[2];
  const float* w1  = (const float*)d_in[3];
  const float* b1  = (const float*)d_in[4];
  const float* g1  = (const float*)d_in[5];
  const float* be1 = (const float*)d_in[6];
  const float* m1  = (const float*)d_in[7];
  const float* v1  = (const float*)d_in[8];
  const float* w2  = (const float*)d_in[9];
  const float* b2  = (const float*)d_in[10];
  const float* g2  = (const float*)d_in[11];
  const float* be2 = (const float*)d_in[12];
  const float* m2  = (const float*)d_in[13];
  const float* v2  = (const float*)d_in[14];
  const float* w3  = (const float*)d_in[15];
  const float* b3  = (const float*)d_in[16];
  const float* g3  = (const float*)d_in[17];
  const float* be3 = (const float*)d_in[18];
  const float* m3  = (const float*)d_in[19];
  const float* v3  = (const float*)d_in[20];
  const float* w4  = (const float*)d_in[21];
  const float* b4  = (const float*)d_in[22];
  const float* g4  = (const float*)d_in[23];
  const float* be4 = (const float*)d_in[24];
  const float* m4  = (const float*)d_in[25];
  const float* v4  = (const float*)d_in[26];

  uint8_t* ws = (uint8_t*)d_ws;
  size_t off = 0;
  auto alloc = [&](size_t bytes) -> void* {
    void* p = ws + off;
    off += (bytes + 255) & ~(size_t)255;
    return p;
  };
  u16* W1f = (u16*)alloc(16 * 17 * 512 * 2);
  u16* W2f = (u16*)alloc(78 * 6 * 512 * 2);
  u16* W3f = (u16*)alloc(16 * 1 * 512 * 2);
  u16* W4f = (u16*)alloc(2 * 4 * 512 * 2);
  float* bias1f = (float*)alloc(272 * 4);
  float* bias2f = (float*)alloc(96 * 4);
  float* bias3f = (float*)alloc(16 * 4);
  float* bias4f = (float*)alloc(64 * 4);
  u16* X0 = (u16*)alloc((size_t)NB * T_LEN * 56 * 2);
  u16* X1 = (u16*)alloc((size_t)NB * T_LEN * 272 * 2);
  u16* X2 = (u16*)alloc((size_t)NB * T_LEN * 96 * 2);

  hipLaunchKernelGGL(conv_poses, dim3(7168), dim3(256), 0, stream, poses, X0);
  hipLaunchKernelGGL(prep_all, dim3(1530), dim3(256), 0, stream,
                     w1, A1, g1, v1, W1f,
                     w2, A2, g2, v2, W2f,
                     w3, g3, v3, W3f,
                     w4, g4, v4, W4f,
                     b1, be1, m1, b2, be2, m2, b3, be3, m3, b4, be4, m4,
                     bias1f, bias2f, bias3f, bias4f);

  hipLaunchKernelGGL(gemm_s1, dim3(32, 16, 2), dim3(192), 0, stream, X0, W1f, bias1f, X1);
  hipLaunchKernelGGL(gemm_s2, dim3(32, 16), dim3(192), 0, stream, X1, W2f, bias2f, X2);
  hipLaunchKernelGGL(gemm34, dim3(64, 16), dim3(256), 0, stream, X2, W3f, bias3f, W4f, bias4f, (float*)d_out);
}